// Round 19
// baseline (1502.450 us; speedup 1.0000x reference)
//
#include <hip/hip_runtime.h>
#include <math.h>

// B=4 N=1024 V=20000 D=512 H=8 DH=64 W=512 NB=2 NS=512 FF=2048

typedef __attribute__((ext_vector_type(8))) _Float16 f16x8;
typedef __attribute__((ext_vector_type(4))) float f32x4;

__device__ __forceinline__ ushort f2h(float f){
  _Float16 h = (_Float16)f;
  return *reinterpret_cast<ushort*>(&h);
}
__device__ __forceinline__ uint pkh2(float a, float b){
  return (uint)f2h(a) | ((uint)f2h(b)<<16);
}

// direct global->LDS async copy, 16B per lane (HW: LDS dst = wave-uniform base
// + lane*16; global src per-lane)
__device__ __forceinline__ void gload16(const ushort* g, ushort* l){
  __builtin_amdgcn_global_load_lds(
      (const __attribute__((address_space(1))) uint*)g,
      (__attribute__((address_space(3))) uint*)l, 16, 0, 0);
}

// ---------------- mega weight prep: 12 transposes in one launch ----------------
struct PrepDescs {
  const float* src[12];
  ushort*      dst[12];
  int K[12], N[12], nx[12], ny[12], cnt[12];
  long zs[12];
};

__global__ __launch_bounds__(256)
void k_prep_all(PrepDescs pd){
  __shared__ float tile[32][33];
  int bid = blockIdx.x, i = 0;
  while (i < 11 && bid >= pd.cnt[i]){ bid -= pd.cnt[i]; i++; }
  const int K = pd.K[i], N = pd.N[i], nx = pd.nx[i];
  const int z = bid/(nx*pd.ny[i]);
  const int rem = bid - z*nx*pd.ny[i];
  const int tyy = rem/nx, txx = rem - tyy*nx;
  const float* src = pd.src[i] + (size_t)z*K*N;
  ushort* dh = pd.dst[i] + (size_t)z*pd.zs[i];
  const int n0 = txx*32, k0 = tyy*32;
  const int tx = threadIdx.x&31, ty = threadIdx.x>>5;
#pragma unroll
  for (int u=0;u<4;u++){
    int kk = k0 + ty + u*8, nn = n0 + tx;
    tile[ty+u*8][tx] = (nn < N) ? src[(size_t)kk*N + nn] : 0.f;
  }
  __syncthreads();
#pragma unroll
  for (int u=0;u<4;u++){
    int nn = n0 + ty + u*8, kk = k0 + tx;
    dh[(size_t)nn*K + kk] = f2h(tile[tx][ty+u*8]);
  }
}

// ---------------- V transpose (startup xl mem only) ----------------
__global__ __launch_bounds__(256)
void k_vtrans(const float* __restrict__ src, ushort* __restrict__ dst,
              long sB, int sR, int sMH, long dB, long dH, int NK){
  __shared__ float tile[64][65];
  int kc = blockIdx.x, h = blockIdx.y, b = blockIdx.z;
  int t = threadIdx.x;
  int key = t>>2, doff = (t&3)*16;
  const float* sp = src + (size_t)b*sB + (size_t)(kc*64+key)*sR + (sMH? h*64:0) + doff;
#pragma unroll
  for (int u=0;u<4;u++){
    float4 v = *reinterpret_cast<const float4*>(sp + u*4);
    tile[key][doff+u*4+0]=v.x; tile[key][doff+u*4+1]=v.y;
    tile[key][doff+u*4+2]=v.z; tile[key][doff+u*4+3]=v.w;
  }
  __syncthreads();
  int d = t>>2, kf = (t&3)*16;
  ushort* dp = dst + (size_t)b*dB + (size_t)h*dH + (size_t)d*NK + kc*64 + kf;
  ushort tmp[16];
#pragma unroll
  for (int u=0;u<16;u++) tmp[u] = f2h(tile[kf+u][d]);
  uint4 o0 = make_uint4((uint)tmp[0]|((uint)tmp[1]<<16), (uint)tmp[2]|((uint)tmp[3]<<16),
                        (uint)tmp[4]|((uint)tmp[5]<<16), (uint)tmp[6]|((uint)tmp[7]<<16));
  uint4 o1 = make_uint4((uint)tmp[8]|((uint)tmp[9]<<16), (uint)tmp[10]|((uint)tmp[11]<<16),
                        (uint)tmp[12]|((uint)tmp[13]<<16),(uint)tmp[14]|((uint)tmp[15]<<16));
  *reinterpret_cast<uint4*>(dp)   = o0;
  *reinterpret_cast<uint4*>(dp+8) = o1;
}

// fp16 -> fp16 transpose (for skv16 V half)
__global__ __launch_bounds__(256)
void k_vtrans16(const ushort* __restrict__ src, ushort* __restrict__ dst,
                long sB, int sR, long dB, int NK){
  __shared__ ushort tile[64][72];
  int kc = blockIdx.x, b = blockIdx.z;
  int t = threadIdx.x;
  int key = t>>2, doff = (t&3)*16;
  const ushort* sp = src + (size_t)b*sB + (size_t)(kc*64+key)*sR + doff;
  *reinterpret_cast<uint4*>(&tile[key][doff])   = *reinterpret_cast<const uint4*>(sp);
  *reinterpret_cast<uint4*>(&tile[key][doff+8]) = *reinterpret_cast<const uint4*>(sp+8);
  __syncthreads();
  int d = t>>2, kf = (t&3)*16;
  ushort* dp = dst + (size_t)b*dB + (size_t)d*NK + kc*64 + kf;
  ushort tmp[16];
#pragma unroll
  for (int u=0;u<16;u++) tmp[u] = tile[kf+u][d];
  uint4 o0 = make_uint4((uint)tmp[0]|((uint)tmp[1]<<16), (uint)tmp[2]|((uint)tmp[3]<<16),
                        (uint)tmp[4]|((uint)tmp[5]<<16), (uint)tmp[6]|((uint)tmp[7]<<16));
  uint4 o1 = make_uint4((uint)tmp[8]|((uint)tmp[9]<<16), (uint)tmp[10]|((uint)tmp[11]<<16),
                        (uint)tmp[12]|((uint)tmp[13]<<16),(uint)tmp[14]|((uint)tmp[15]<<16));
  *reinterpret_cast<uint4*>(dp)   = o0;
  *reinterpret_cast<uint4*>(dp+8) = o1;
}

__global__ void k_cvt(ushort* __restrict__ dst, const float* __restrict__ src, int n2){
  int idx = blockIdx.x*blockDim.x + threadIdx.x;
  if (idx >= n2) return;
  reinterpret_cast<uint*>(dst)[idx] = pkh2(src[2*idx], src[2*idx+1]);
}

// ---------------- embed / postable ----------------
__global__ void k_embed(const int* __restrict__ x, const float* __restrict__ emb,
                        float* __restrict__ h, int total4){
  int idx = blockIdx.x*blockDim.x + threadIdx.x;
  if (idx >= total4) return;
  int row = idx >> 7;
  int c4  = idx & 127;
  int tok = x[row];
  reinterpret_cast<float4*>(h)[idx] =
      reinterpret_cast<const float4*>(emb)[(size_t)tok*128 + c4];
}

__global__ void k_postable(const float* __restrict__ w1, const float* __restrict__ b1,
                           const float* __restrict__ w2, const float* __restrict__ b2,
                           const float* __restrict__ w3, const float* __restrict__ b3,
                           float* __restrict__ table){
  __shared__ float h1[128];
  __shared__ float h2[128];
  int d = blockIdx.x, t = threadIdx.x;
  float a = (float)d * w1[t] + b1[t];
  h1[t] = a / (1.f + __expf(-a));
  __syncthreads();
  float acc = b2[t];
  for (int p=0;p<128;p++) acc += h1[p]*w2[p*128+t];
  h2[t] = acc / (1.f + __expf(-acc));
  __syncthreads();
  if (t < 8){
    float acc2 = b3[t];
    for (int p=0;p<128;p++) acc2 += h2[p]*w3[p*8+t];
    table[d*8+t] = acc2;
  }
}

// ---------------- layernorm -> fp16 ----------------
__global__ void k_ln(const float* __restrict__ x, const float* __restrict__ g,
                     ushort* __restrict__ y16){
  int row = blockIdx.x;
  int t = threadIdx.x;
  float2 v = reinterpret_cast<const float2*>(x + (size_t)row*512)[t];
  float s = v.x+v.y, ss = v.x*v.x+v.y*v.y;
  for (int o=32;o;o>>=1){ s += __shfl_down(s,o); ss += __shfl_down(ss,o); }
  __shared__ float ls[4], lss[4];
  __shared__ float smu, srs;
  int wid = t>>6;
  if ((t&63)==0){ ls[wid]=s; lss[wid]=ss; }
  __syncthreads();
  if (t==0){
    float S=ls[0]+ls[1]+ls[2]+ls[3], SS=lss[0]+lss[1]+lss[2]+lss[3];
    float mu = S*(1.f/512.f);
    float var = SS*(1.f/512.f) - mu*mu;
    smu = mu; srs = rsqrtf(var + 1e-5f);
  }
  __syncthreads();
  float mu=smu, rs=srs;
  float2 gg = reinterpret_cast<const float2*>(g)[t];
  float ya = (v.x-mu)*rs*gg.x, yb = (v.y-mu)*rs*gg.y;
  *reinterpret_cast<uint*>(&y16[(size_t)row*512 + 2*t]) = pkh2(ya, yb);
}

__device__ __forceinline__ float geluf(float x){
  float u = 1.5957691216f*(x + 0.044715f*x*x*x);
  return x / (1.f + __expf(-u));
}

// ---------------- fp16 MFMA GEMM 128x128 (FF1, logits) -----------------------
// global_load_lds staging (width 16) into LINEAR [128][64] LDS tiles.
// Values identical to reg-staged version (pure copies; same MFMA order).
template<int ACC, int EPI, int OUT16>
__global__ __launch_bounds__(256)
void k_gemmh(const ushort* __restrict__ A, const ushort* __restrict__ Bt,
             const float* __restrict__ bias, float* __restrict__ C,
             ushort* __restrict__ C16, int M, int N, int K){
  __shared__ ushort As[8192];      // [128][64] linear
  __shared__ ushort Bs[8192];
  const int t = threadIdx.x;
  const int m0 = blockIdx.x*128, n0 = blockIdx.y*128;
  const int w = t>>6, lane = t&63;
  const int wm = (w>>1)*64, wn = (w&1)*64;
  const int fr = lane&15, fg = lane>>4;
  const int srow0 = lane>>3, scol = (lane&7)*8;   // per-lane within 1KB chunk

  f32x4 acc[4][4];
#pragma unroll
  for (int i=0;i<4;i++)
#pragma unroll
    for (int j=0;j<4;j++){ acc[i][j][0]=0.f; acc[i][j][1]=0.f; acc[i][j][2]=0.f; acc[i][j][3]=0.f; }

  for (int k0=0; k0<K; k0+=64){
#pragma unroll
    for (int u=0;u<4;u++){
      int chunk = w*4 + u;                 // 0..15, 8 rows each
      int row = chunk*8 + srow0;
      gload16(A  + (size_t)(m0+row)*K + k0 + scol, &As[chunk*512]);
      gload16(Bt + (size_t)(n0+row)*K + k0 + scol, &Bs[chunk*512]);
    }
    __syncthreads();
#pragma unroll
    for (int kk=0;kk<2;kk++){
      f16x8 af[4], bf[4];
#pragma unroll
      for (int mi=0;mi<4;mi++)
        af[mi] = *reinterpret_cast<const f16x8*>(&As[(wm+mi*16+fr)*64 + kk*32+fg*8]);
#pragma unroll
      for (int nj=0;nj<4;nj++)
        bf[nj] = *reinterpret_cast<const f16x8*>(&Bs[(wn+nj*16+fr)*64 + kk*32+fg*8]);
#pragma unroll
      for (int mi=0;mi<4;mi++)
#pragma unroll
        for (int nj=0;nj<4;nj++)
          acc[mi][nj] = __builtin_amdgcn_mfma_f32_16x16x32_f16(af[mi], bf[nj], acc[mi][nj], 0,0,0);
    }
    __syncthreads();
  }
#pragma unroll
  for (int mi=0;mi<4;mi++){
#pragma unroll
    for (int r=0;r<4;r++){
      int row = m0 + wm + mi*16 + fg*4 + r;
#pragma unroll
      for (int nj=0;nj<4;nj++){
        int col = n0 + wn + nj*16 + fr;
        if (col < N){
          float val = acc[mi][nj][r];
          if (bias) val += bias[col];
          if (EPI==1) val = geluf(val);
          if (OUT16){
            C16[(size_t)row*N + col] = f2h(val);
          } else {
            if (ACC) C[(size_t)row*N + col] += val; else C[(size_t)row*N + col] = val;
          }
        }
      }
    }
  }
}

// ---------------- fp16 MFMA GEMM 128x128 with split out + rms + remap --------
template<int REMAP>
__global__ __launch_bounds__(256)
void k_gemmqk(const ushort* __restrict__ A, const ushort* __restrict__ Bt,
              ushort* __restrict__ C1h, int ld1, int N1,
              ushort* __restrict__ C2h, int ld2,
              const float* __restrict__ qsc, const float* __restrict__ ksc,
              float* __restrict__ xlk,
              int nb, int M, int N, int K){
  __shared__ ushort As[128][68];
  __shared__ ushort Bs[128][68];
  const int t = threadIdx.x;
  const int m0 = blockIdx.x*128, n0 = blockIdx.y*128;
  const int w = t>>6, lane = t&63;
  const int wm = (w>>1)*64, wn = (w&1)*64;
  const int fr = lane&15, fg = lane>>4;
  const int srow = t>>1, sko = (t&1)*32;

  f32x4 acc[4][4];
#pragma unroll
  for (int i=0;i<4;i++)
#pragma unroll
    for (int j=0;j<4;j++){ acc[i][j][0]=0.f; acc[i][j][1]=0.f; acc[i][j][2]=0.f; acc[i][j][3]=0.f; }

  int mrow = m0 + srow;
  int arow = REMAP ? ((mrow>>9)*1024 + nb*512 + (mrow&511)) : mrow;
  const ushort* ap = A  + (size_t)arow*K + sko;
  const ushort* bp = Bt + (size_t)(n0+srow)*K + sko;

  for (int k0=0; k0<K; k0+=64){
    uint4 av[4], bv[4];
#pragma unroll
    for (int u=0;u<4;u++){
      av[u] = *reinterpret_cast<const uint4*>(ap + k0 + u*8);
      bv[u] = *reinterpret_cast<const uint4*>(bp + k0 + u*8);
    }
#pragma unroll
    for (int u=0;u<4;u++){
      *reinterpret_cast<uint4*>(&As[srow][sko+u*8]) = av[u];
      *reinterpret_cast<uint4*>(&Bs[srow][sko+u*8]) = bv[u];
    }
    __syncthreads();
#pragma unroll
    for (int kk=0;kk<2;kk++){
      f16x8 af[4], bf[4];
#pragma unroll
      for (int mi=0;mi<4;mi++)
        af[mi] = *reinterpret_cast<const f16x8*>(&As[wm+mi*16+fr][kk*32+fg*8]);
#pragma unroll
      for (int nj=0;nj<4;nj++)
        bf[nj] = *reinterpret_cast<const f16x8*>(&Bs[wn+nj*16+fr][kk*32+fg*8]);
#pragma unroll
      for (int mi=0;mi<4;mi++)
#pragma unroll
        for (int nj=0;nj<4;nj++)
          acc[mi][nj] = __builtin_amdgcn_mfma_f32_16x16x32_f16(af[mi], bf[nj], acc[mi][nj], 0,0,0);
    }
    __syncthreads();
  }
#pragma unroll
  for (int mi=0;mi<4;mi++){
#pragma unroll
    for (int r=0;r<4;r++){
      int row = m0 + wm + mi*16 + fg*4 + r;
      float vals[4];
#pragma unroll
      for (int nj=0;nj<4;nj++) vals[nj] = acc[mi][nj][r];
      if (qsc){
        float ss = vals[0]*vals[0]+vals[1]*vals[1]+vals[2]*vals[2]+vals[3]*vals[3];
        ss += __shfl_xor(ss,1);
        ss += __shfl_xor(ss,2);
        ss += __shfl_xor(ss,4);
        ss += __shfl_xor(ss,8);
        float rs = rsqrtf(ss + 1e-12f);
        const float* sc = ((n0+wn) < N1) ? qsc : ksc;
#pragma unroll
        for (int nj=0;nj<4;nj++) vals[nj] = vals[nj]*rs*sc[nj*16+fr];
      }
#pragma unroll
      for (int nj=0;nj<4;nj++){
        int col = n0 + wn + nj*16 + fr;
        float val = vals[nj];
        if (col < N1){
          C1h[(size_t)row*ld1 + col] = f2h(val);
        } else if (col < N){
          if (C2h) C2h[(size_t)row*ld2 + (col-N1)] = f2h(val);
          if (xlk && (row&1023) >= 512)
            xlk[((size_t)(row>>10)*512 + (row&1023) - 512)*512 + (col-N1)] = val;
        }
      }
    }
  }
}

// ---------------- fp16 MFMA GEMM 64x128 (N=512 class) ------------------------
// EPI: 0 none, 1 gelu, 2 ema. VT=1: fp16 transposed vT + optional fp32 xlv.
template<int ACC, int EPI, int OUT16, int VT>
__global__ __launch_bounds__(256)
void k_gemmh64(const ushort* __restrict__ A, const ushort* __restrict__ Bt,
               const float* __restrict__ bias, float* __restrict__ C,
               ushort* __restrict__ C16, ushort* __restrict__ vT,
               float* __restrict__ xlv, int M, int N, int K){
  __shared__ ushort As[64][68];
  __shared__ ushort Bs[128][68];
  const int t = threadIdx.x;
  const int m0 = blockIdx.x*64, n0 = blockIdx.y*128;
  const int w = t>>6, lane = t&63;
  const int wm = (w>>1)*32, wn = (w&1)*64;
  const int fr = lane&15, fg = lane>>4;
  const int srowA = t>>2, skoA = (t&3)*16;
  const int srowB = t>>1, skoB = (t&1)*32;

  f32x4 acc[2][4];
#pragma unroll
  for (int i=0;i<2;i++)
#pragma unroll
    for (int j=0;j<4;j++){ acc[i][j][0]=0.f; acc[i][j][1]=0.f; acc[i][j][2]=0.f; acc[i][j][3]=0.f; }

  const ushort* ap = A  + (size_t)(m0+srowA)*K + skoA;
  const ushort* bp = Bt + (size_t)(n0+srowB)*K + skoB;

  for (int k0=0; k0<K; k0+=64){
    uint4 a0 = *reinterpret_cast<const uint4*>(ap + k0);
    uint4 a1 = *reinterpret_cast<const uint4*>(ap + k0 + 8);
    uint4 b0 = *reinterpret_cast<const uint4*>(bp + k0);
    uint4 b1 = *reinterpret_cast<const uint4*>(bp + k0 + 8);
    uint4 b2 = *reinterpret_cast<const uint4*>(bp + k0 + 16);
    uint4 b3 = *reinterpret_cast<const uint4*>(bp + k0 + 24);
    *reinterpret_cast<uint4*>(&As[srowA][skoA])    = a0;
    *reinterpret_cast<uint4*>(&As[srowA][skoA+8])  = a1;
    *reinterpret_cast<uint4*>(&Bs[srowB][skoB])    = b0;
    *reinterpret_cast<uint4*>(&Bs[srowB][skoB+8])  = b1;
    *reinterpret_cast<uint4*>(&Bs[srowB][skoB+16]) = b2;
    *reinterpret_cast<uint4*>(&Bs[srowB][skoB+24]) = b3;
    __syncthreads();
#pragma unroll
    for (int kk=0;kk<2;kk++){
      f16x8 af[2], bf[4];
#pragma unroll
      for (int mi=0;mi<2;mi++)
        af[mi] = *reinterpret_cast<const f16x8*>(&As[wm+mi*16+fr][kk*32+fg*8]);
#pragma unroll
      for (int nj=0;nj<4;nj++)
        bf[nj] = *reinterpret_cast<const f16x8*>(&Bs[wn+nj*16+fr][kk*32+fg*8]);
#pragma unroll
      for (int mi=0;mi<2;mi++)
#pragma unroll
        for (int nj=0;nj<4;nj++)
          acc[mi][nj] = __builtin_amdgcn_mfma_f32_16x16x32_f16(af[mi], bf[nj], acc[mi][nj], 0,0,0);
    }
    __syncthreads();
  }
#pragma unroll
  for (int mi=0;mi<2;mi++){
#pragma unroll
    for (int r=0;r<4;r++){
      int row = m0 + wm + mi*16 + fg*4 + r;
#pragma unroll
      for (int nj=0;nj<4;nj++){
        int col = n0 + wn + nj*16 + fr;
        if (col < N){
          float val = acc[mi][nj][r];
          if (EPI==2){
            size_t idx = (size_t)row*N + col;
            float old = C[idx];
            float dec = 1.f/(1.f+__expf(-bias[col]));
            C[idx] = dec*old + (1.f-dec)*val;
          } else {
            if (bias) val += bias[col];
            if (EPI==1) val = geluf(val);
            if (OUT16){
              if (C16) C16[(size_t)row*N + col] = f2h(val);
            } else if (C){
              if (ACC) C[(size_t)row*N + col] += val; else C[(size_t)row*N + col] = val;
            }
            if (VT && xlv && (row&1023) >= 512)
              xlv[((size_t)(row>>10)*512 + (row&1023) - 512)*512 + col] = val;
          }
        }
      }
    }
  }
  if (VT){
#pragma unroll
    for (int mi=0;mi<2;mi++)
#pragma unroll
      for (int r=0;r<4;r++)
#pragma unroll
        for (int nj=0;nj<4;nj++)
          Bs[wn+nj*16+fr][wm+mi*16+fg*4+r] = f2h(acc[mi][nj][r]);
    __syncthreads();
    int c = t>>1, half = t&1;
    int hh = (n0+c)>>6, dd = (n0+c)&63;
    int bb = m0>>10, posb = m0&1023;
    ushort* dp = vT + (size_t)bb*524288 + (size_t)hh*65536 + (size_t)dd*1024 + posb + half*32;
#pragma unroll
    for (int u=0;u<4;u++)
      *reinterpret_cast<uint4*>(dp + u*8) = *reinterpret_cast<const uint4*>(&Bs[c][half*32 + u*8]);
  }
}

// ---------------- merged windowed MFMA flash attention -----------------------
__global__ __launch_bounds__(256)
void k_attn_win(const ushort* __restrict__ q16, const ushort* __restrict__ k16,
                const ushort* __restrict__ vTb,
                const ushort* __restrict__ xlK, const ushort* __restrict__ xlVT,
                int isxl, ushort* __restrict__ O, float scale,
                const float* __restrict__ table){
  __shared__ ushort Qs[64][72];
  __shared__ ushort Ks[64][72];
  __shared__ ushort Vs[64][72];
  __shared__ ushort Pw[4][16][72];
  __shared__ float tcol[512];
  const int b = blockIdx.z, h = blockIdx.y;
  const int nb = blockIdx.x>>3, qt = blockIdx.x&7;
  const int t = threadIdx.x, w = t>>6, lane = t&63;
  const int fr = lane&15, fg = lane>>4;
  tcol[t]     = table[t*8 + h];
  tcol[t+256] = table[(t+256)*8 + h];

  const ushort* Q  = q16 + (size_t)nb*262144;
  const ushort* K1 = k16 + (size_t)nb*262144;
  const ushort* V1 = vTb + (size_t)nb*512;
  ushort* Op = O + (size_t)nb*262144;
  const int has_mem = (nb==1) || isxl;
  const ushort* K0; long k0B; const ushort* V0; long vt0B, vt0H; int vt0D;
  if (nb==1){ K0=k16; k0B=524288; V0=vTb; vt0B=524288; vt0H=65536; vt0D=1024; }
  else if (isxl){ K0=xlK; k0B=262144; V0=xlVT; vt0B=262144; vt0H=32768; vt0D=512; }
  else { K0=k16; k0B=524288; V0=vTb; vt0B=524288; vt0H=65536; vt0D=1024; }

  {
    int qrow = t>>2, doff = (t&3)*16;
    const ushort* qp = Q + (size_t)b*524288 + (size_t)(qt*64+qrow)*512 + h*64 + doff;
    *reinterpret_cast<uint4*>(&Qs[qrow][doff])   = *reinterpret_cast<const uint4*>(qp);
    *reinterpret_cast<uint4*>(&Qs[qrow][doff+8]) = *reinterpret_cast<const uint4*>(qp+8);
  }
  __syncthreads();
  f16x8 aq[2];
  aq[0] = *reinterpret_cast<const f16x8*>(&Qs[w*16+fr][fg*8]);
  aq[1] = *reinterpret_cast<const f16x8*>(&Qs[w*16+fr][32+fg*8]);

  f32x4 so[4];
#pragma unroll
  for (int dt=0;dt<4;dt++){ so[dt][0]=0.f; so[dt][1]=0.f; so[dt][2]=0.f; so[dt][3]=0.f; }
  float m[4] = {-1e30f,-1e30f,-1e30f,-1e30f};
  float lsum[4] = {0.f,0.f,0.f,0.f};

  const int srow = t>>2, sdo = (t&3)*16;
  const int vd = t>>2,   vkf = (t&3)*16;

  int jt0 = has_mem ? qt : 8;
  int jt1 = qt + 8; if (jt1 > 15) jt1 = 15;

  for (int jt=jt0; jt<=jt1; jt++){
    {
      int key = jt*64 + srow;
      const ushort* kp;
      if (key < 512) kp = K0 + (size_t)b*k0B + (size_t)key*512 + h*64 + sdo;
      else           kp = K1 + (size_t)b*524288 + (size_t)(key-512)*512 + h*64 + sdo;
      *reinterpret_cast<uint4*>(&Ks[srow][sdo])   = *reinterpret_cast<const uint4*>(kp);
      *reinterpret_cast<uint4*>(&Ks[srow][sdo+8]) = *reinterpret_cast<const uint4*>(kp+8);
    }
    {
      const ushort* vp;
      if (jt*64 < 512) vp = V0 + (size_t)b*vt0B + (size_t)h*vt0H + (size_t)vd*vt0D + jt*64 + vkf;
      else             vp = V1 + (size_t)b*524288 + (size_t)h*65536 + (size_t)vd*1024 + (jt*64-512) + vkf;
      *reinterpret_cast<uint4*>(&Vs[vd][vkf])   = *reinterpret_cast<const uint4*>(vp);
      *reinterpret_cast<uint4*>(&Vs[vd][vkf+8]) = *reinterpret_cast<const uint4*>(vp+8);
    }
    __syncthreads();
    f32x4 sacc[4];
#pragma unroll
    for (int kt=0;kt<4;kt++){ sacc[kt][0]=0.f; sacc[kt][1]=0.f; sacc[kt][2]=0.f; sacc[kt][3]=0.f; }
#pragma unroll
    for (int ks=0;ks<2;ks++){
#pragma unroll
      for (int kt=0;kt<4;kt++){
        f16x8 bf = *reinterpret_cast<const f16x8*>(&Ks[kt*16+fr][ks*32+fg*8]);
        sacc[kt] = __builtin_amdgcn_mfma_f32_16x16x32_f16(aq[ks], bf, sacc[kt], 0,0,0);
      }
    }
#pragma unroll
    for (int r=0;r<4;r++){
      float sv[4];
      int ia = qt*64 + w*16 + fg*4 + r;
#pragma unroll
      for (int kt=0;kt<4;kt++){
        float s = sacc[kt][r]*scale;
        int jg = jt*64 + kt*16 + fr;
        bool valid = (jg > ia) && (jg <= ia+512) && (has_mem || jg >= 512);
        sv[kt] = valid ? s + tcol[ia+512-jg] : -1e9f;
      }
      float tm = fmaxf(fmaxf(sv[0],sv[1]), fmaxf(sv[2],sv[3]));
      tm = fmaxf(tm, __shfl_xor(tm,1));
      tm = fmaxf(tm, __shfl_xor(tm,2));
      tm = fmaxf(tm, __shfl_xor(tm,4));
      tm = fmaxf(tm, __shfl_xor(tm,8));
      float mn = fmaxf(m[r], tm);
      float c = __expf(m[r]-mn);
      m[r] = mn;
      float ps = 0.f;
#pragma unroll
      for (int kt=0;kt<4;kt++){
        float pp = (sv[kt] <= -1e8f) ? 0.f : __expf(sv[kt]-mn);
        ps += pp;
        Pw[w][fg*4+r][kt*16+fr] = f2h(pp);
      }
      ps += __shfl_xor(ps,1);
      ps += __shfl_xor(ps,2);
      ps += __shfl_xor(ps,4);
      ps += __shfl_xor(ps,8);
      lsum[r] = lsum[r]*c + ps;
#pragma unroll
      for (int dt=0;dt<4;dt++) so[dt][r] *= c;
    }
#pragma unroll
    for (int ks=0;ks<2;ks++){
      f16x8 pa = *reinterpret_cast<const f16x8*>(&Pw[w][fr][ks*32+fg*8]);
#pragma unroll
      for (int dt=0;dt<4;dt++){
        f16x8 bv = *reinterpret_cast<const f16x8*>(&Vs[dt*16+fr][ks*32+fg*8]);
        so[dt] = __builtin_amdgcn_mfma_f32_16x16x32_f16(pa, bv, so[dt], 0,0,0);
      }
    }
    __syncthreads();
  }
#pragma unroll
  for (int r=0;r<4;r++){
    int row = qt*64 + w*16 + fg*4 + r;
    float inv = 1.f / lsum[r];
    ushort* op = Op + (size_t)b*524288 + (size_t)row*512 + h*64;
#pragma unroll
    for (int dt=0;dt<4;dt++)
      op[dt*16+fr] = f2h(so[dt][r]*inv);
  }
}

// ---------------- merged rec-layer attentions ----------------
__global__ __launch_bounds__(256)
void k_attn_rec(const ushort* __restrict__ q2s, const ushort* __restrict__ sq,
                const ushort* __restrict__ skv, const ushort* __restrict__ svT,
                const ushort* __restrict__ kblk, const ushort* __restrict__ vblk,
                ushort* __restrict__ ts, ushort* __restrict__ sa){
  __shared__ ushort Qs[64][72];
  __shared__ ushort Ks[64][72];
  __shared__ ushort Vs[64][72];
  __shared__ ushort Pw[4][16][72];
  const int b = blockIdx.z, h = blockIdx.y;
  const int task = blockIdx.x>>3, qt = blockIdx.x&7;
  const int t = threadIdx.x, w = t>>6, lane = t&63;
  const int fr = lane&15, fg = lane>>4;

  const ushort* Q; const ushort* K1; int k1R, k1H;
  const ushort* VT1; long vt1B, vt1H; int vt1D;
  int nt; ushort* O; long oB;
  if (task==0){
    Q=q2s; K1=skv; k1R=128; k1H=0;
    VT1=svT; vt1B=32768; vt1H=0; vt1D=512;
    nt=8; O=ts; oB=524288;
  } else {
    Q=sq; K1=kblk; k1R=512; k1H=1;
    VT1=vblk; vt1B=524288; vt1H=65536; vt1D=1024;
    nt=16; O=sa; oB=262144;
  }

  {
    int qrow = t>>2, doff = (t&3)*16;
    const ushort* qp = Q + (size_t)b*262144 + (size_t)(qt*64+qrow)*512 + h*64 + doff;
    *reinterpret_cast<uint4*>(&Qs[qrow][doff])   = *reinterpret_cast<const uint4*>(qp);
    *reinterpret_cast<uint4*>(&Qs[qrow][doff+8]) = *reinterpret_cast<const uint4*>(qp+8);
  }
  __syncthreads();
  f16x8 aq[2];
  aq[0] = *reinterpret_cast<const f16x8*>(&Qs[w*16+fr][fg*8]);
  aq[1] = *reinterpret_cast<const f16x8*>(&Qs[w*16+fr][32+fg*8]);

  f32x4 so[4];
#pragma unroll
  for (int dt=0;dt<4;dt++){ so[dt][0]=0.f; so[dt][1]=0.f; so[dt][2]=0.f; so[dt][3]=0.f; }
  float m[4] = {-1e30f,-1e30f,-1e30f,-1e30f};
  float lsum[4] = {0.f,0.f,0.f,0.f};

  const int srow = t>>2, sdo = (t&3)*16;
  const int vd = t>>2,   vkf = (t&3)*16;

  for (int jt=0; jt<nt; jt++){
    {
      int key = jt*64 + srow;
      const ushort* kp;
      if (key < 512) kp = skv + (size_t)b*65536 + (size_t)key*128 + sdo;
      else           kp = K1 + (size_t)b*524288 + (size_t)(key-512)*k1R + (k1H? h*64:0) + sdo;
      *reinterpret_cast<uint4*>(&Ks[srow][sdo])   = *reinterpret_cast<const uint4*>(kp);
      *reinterpret_cast<uint4*>(&Ks[srow][sdo+8]) = *reinterpret_cast<const uint4*>(kp+8);
    }
    {
      const ushort* vp;
      if (jt*64 < 512) vp = svT + (size_t)b*32768 + (size_t)vd*512 + jt*64 + vkf;
      else             vp = VT1 + (size_t)b*vt1B + (size_t)h*vt1H + (size_t)vd*vt1D + (jt*64-512) + vkf;
      *reinterpret_cast<uint4*>(&Vs[vd][vkf])   = *reinterpret_cast<const uint4*>(vp);
      *reinterpret_cast<uint4*>(&Vs[vd][vkf+8]) = *reinterpret_cast<const uint4*>(vp+8);
    }
    __syncthreads();
    f32x4 sacc[4];
#pragma unroll
    for (int kt=0;kt<4;kt++){ sacc[kt][0]=0.f; sacc[kt][1]=0.f; sacc[kt][2]=0.f; sacc[kt][3]=0.f; }
#pragma unroll
    for (int ks=0;ks<2;ks++){
#pragma unroll
      for (int kt=0;kt<4;kt++){
        f16x8 bf = *reinterpret_cast<const f16x8*>(&Ks[kt*16+fr][ks*32+fg*8]);
        sacc[kt] = __builtin_amdgcn_mfma_f32_16x16x32_f16(aq[ks], bf, sacc[kt], 0,0,0);
      }
    }
#pragma unroll
    for (int r=0;r<4;r++){
      float sv[4];
#pragma unroll
      for (int kt=0;kt<4;kt++) sv[kt] = sacc[kt][r]*0.125f;
      float tm = fmaxf(fmaxf(sv[0],sv[1]), fmaxf(sv[2],sv[3]));
      tm = fmaxf(tm, __shfl_xor(tm,1));
      tm = fmaxf(tm, __shfl_xor(tm,2));
      tm = fmaxf(tm, __shfl_xor(tm,4));
      tm = fmaxf(tm, __shfl_xor(tm,8));
      float mn = fmaxf(m[r], tm);
      float c = __expf(m[r]-mn);
      m[r] = mn;
      float ps = 0.f;
#pragma unroll
      for (int kt=0;kt<4;kt++){
        float pp = __expf(sv[kt]-mn);
        ps += pp;
        Pw[w][fg*4+r][kt*16+fr] = f2h(pp);
      }
      ps += __shfl_xor(ps,1);
      ps += __shfl_xor(ps,2);
      ps += __shfl_xor(ps,4);
      ps += __shfl_xor(ps,8);
      lsum[r] = lsum[r]*c + ps;
#pragma unroll
      for (int dt=0;dt<4;dt++) so[dt][r] *= c;
    }
#pragma unroll
    for (int ks=0;ks<2;ks++){
      f16x8 pa = *reinterpret_cast<const f16x8*>(&Pw[w][fr][ks*32+fg*8]);
#pragma unroll
      for (int dt=0;dt<4;dt++){
        f16x8 bv = *reinterpret_cast<const f16x8*>(&Vs[dt*16+fr][ks*32+fg*8]);
        so[dt] = __builtin_amdgcn_mfma_f32_16x16x32_f16(pa, bv, so[dt], 0,0,0);
      }
    }
    __syncthreads();
  }
#pragma unroll
  for (int r=0;r<4;r++){
    int row = qt*64 + w*16 + fg*4 + r;
    float inv = 1.f / lsum[r];
    ushort* op = O + (size_t)b*oB + (size_t)row*512 + h*64;
#pragma unroll
    for (int dt=0;dt<4;dt++)
      op[dt*16+fr] = f2h(so[dt][r]*inv);
  }
}

// ---------------- small utility kernels ----------------
__global__ void k_copy(float* __restrict__ dst, const float* __restrict__ src, int n){
  int idx = blockIdx.x*blockDim.x + threadIdx.x;
  if (idx < n) dst[idx] = src[idx];
}

// ---------------- launcher ----------------
extern "C" void kernel_launch(void* const* d_in, const int* in_sizes, int n_in,
                              void* d_out, int out_size, void* d_ws, size_t ws_size,
                              hipStream_t stream){
  // floats 12,599,296 B + ushorts 106,954,752 B = 119,554,048 B
  if (ws_size < (size_t)119554048) return;

  const int*   x        = (const int*)  d_in[0];
  const float* tok_emb  = (const float*)d_in[1];
  const float* pw1 = (const float*)d_in[2];
  const float* pb1 = (const float*)d_in[3];
  const float* pw2 = (const float*)d_in[4];
  const float* pb2 = (const float*)d_in[5];
  const float* pw3 = (const float*)d_in[6];
  const float* pb3 = (const float*)d_in[7];
  const float* ln_g = (const float*)d_in[8];
  const float* Wq = (const float*)d_in[9];
  const float* Wk = (const float*)d_in[10];
  const float* Wv = (const float*)d_in[11];
  const float* Wo = (const float*)d_in[12];
  const float* q_scale = (const float*)d_in[13];
  const float* k_scale = (const float*)d_in[14];
  const float* Wo_state = (const float*)d_in[15];
  const float* state_norm_g = (const float*)d_in[16];
  const float* Wq2s = (const float*)d_in[17];
  const float* Ws2q = (const float*)d_in[18];
  const float* Ws2kv = (const float*)d_in[19];
  const float* W_state_out = (const float*)d_in[20];
  const float* ema_beta = (const float*)d_in[21];
  const float* ff_g = (const float*)d_in[22];
  const float* ff_w1 = (const float*)d_in[23];
  const float* ff_b1 = (const float*)d_in[24];
  const float* ff_w2 = (const float*)d_in[25];
  const float* ff_b2 = (const float*)d_in[26];
  const float* final_g = (const float*)d_in[27];
  const float* W_logits = (const float*)d_in[28];
  const float* xl_mem_k = (const float*)d_in[29];
  const float* xl_mem_v = (const float*)d_in[30];
  const float* states_in = (const float*)d_in[31];

  float* out = (float*)d_out;
  float* out_xlk    = out + 81920000;
  float* out_xlv    = out + 84017152;
  float* out_states = out + 86114304;

  float* p = (float*)d_ws;
  float* hstate   = p; p += 2097152;
  float* states_cur = p; p += 1048576;
  float* table    = p; p += 4096;

  ushort* us = (ushort*)p;
  ushort* wqkh  = us; us += 3145728;   // [6][1024][512]: rows 0-511 q, 512-1023 k
  ushort* wvT   = us; us += 1572864;
  ushort* woT   = us; us += 1572864;
  ushort* ffw1T = us; us += 6291456;
  ushort* ffw2T = us; us += 6291456;
  ushort* wostT = us; us += 262144;
  ushort* wstoutT = us; us += 262144;
  ushort* wq2sh = us; us += 262144;
  ushort* wsqkvh = us; us += 327680;   // [640][512]: rows 0-511 Ws2q, 512-639 Ws2kv
  ushort* wlogT  = us; us += 10289152; // [20096][512]
  ushort* vTb   = us; us += 2097152;   // [b][h][64][1024]
  ushort* xlvT  = us; us += 2097152;   // [2][b][h][64][512]
  ushort* svT   = us; us += 131072;    // [b][64][512]
  ushort* xn16  = us; us += 2097152;
  ushort* ao16  = us; us += 2097152;
  ushort* ff1_16 = us; us += 8388608;  // [4096][2048] + rec aliases
  ushort* q16   = us; us += 2097152;
  ushort* k16   = us; us += 2097152;
  ushort* xlk16 = us; us += 2097152;   // [2][b][512][512] fp16
  // rec aliases inside ff1_16 (dead between FF uses)
  ushort* ts16   = ff1_16;             // [4096][512]
  ushort* sa16   = ff1_16 + 2097152;   // [2048][512]
  ushort* sn16   = ff1_16 + 3145728;   // [2048][512]
  ushort* sq16   = ff1_16 + 4194304;   // [2048][512]
  ushort* q2s16  = ff1_16 + 5242880;   // [2048][512]
  ushort* skv16  = ff1_16 + 6291456;   // [2048][128]

  // ---- mega weight prep (single launch; same per-tile math as 12 k_prep calls)
  PrepDescs pd;
  auto setd = [&](int i, const float* s, ushort* d, int K, int N, int nx, int ny, int nz, long zs){
    pd.src[i]=s; pd.dst[i]=d; pd.K[i]=K; pd.N[i]=N; pd.nx[i]=nx; pd.ny[i]=ny;
    pd.cnt[i]=nx*ny*nz; pd.zs[i]=zs;
  };
  setd(0,  Wq,          wqkh,           512,512,  16,16,6, 524288);
  setd(1,  Wk,          wqkh+262144,    512,512,  16,16,6, 524288);
  setd(2,  Wv,          wvT,            512,512,  16,16,6, 262144);
  setd(3,  Wo,          woT,            512,512,  16,16,6, 262144);
  setd(4,  ff_w1,       ffw1T,          512,2048, 64,16,6, 1048576);
  setd(5,  ff_w2,       ffw2T,          2048,512, 16,64,6, 1048576);
  setd(6,  Wo_state,    wostT,          512,512,  16,16,1, 262144);
  setd(7,  W_state_out, wstoutT,        512,512,  16,16,1, 262144);
  setd(8,  Wq2s,        wq2sh,          512,512,  16,16,1, 262144);
  setd(9,  Ws2q,        wsqkvh,         512,512,  16,16,1, 327680);
  setd(10, Ws2kv,       wsqkvh+262144,  512,128,  4,16,1,  327680);
  setd(11, W_logits,    wlogT,          512,20000,628,16,1,10289152);
  k_prep_all<<<29568,256,0,stream>>>(pd);

  for (int s=0;s<2;s++)
    k_vtrans<<<dim3(8,8,4),256,0,stream>>>(xl_mem_v + (size_t)s*1048576,
                                           xlvT + (size_t)s*1048576,
                                           262144L, 512, 1, 262144L, 32768L, 512);
  k_cvt<<<4096,256,0,stream>>>(xlk16, xl_mem_k, 1048576);

  k_embed<<<2048, 256, 0, stream>>>(x, tok_emb, hstate, 524288);
  k_postable<<<512, 128, 0, stream>>>(pw1,pb1,pw2,pb2,pw3,pb3, table);
  k_copy<<<4096, 256, 0, stream>>>(states_cur, states_in, 1048576);

  for (int l=0;l<6;l++){
    bool isxl = (l==4 || l==5);
    int xli = l-4;
    int src = (l==4)? 1 : 0;     // roll(-1)
    k_ln<<<4096,256,0,stream>>>(hstate, ln_g + l*512, xn16);
    float scale = 0.125f;
    const float* qsc = nullptr; const float* ksc = nullptr;
    if (l>=3){ qsc = q_scale + l*64; ksc = k_scale + l*64; scale = 8.f; }
    // q|k merged fp16 GEMM with fused rmsnorm (l>=3) + xl-k fp32 out (l=4,5)
    k_gemmqk<0><<<dim3(32,8),256,0,stream>>>(xn16,
        wqkh + (size_t)l*524288,
        q16, 512, 512, k16, 512, qsc, ksc,
        isxl ? out_xlk + (size_t)xli*1048576 : nullptr,
        0, 4096, 1024, 512);
    // v GEMM: fp16 V^T + (xl) fp32 out_xlv
    k_gemmh64<0,0,0,1><<<dim3(64,4),256,0,stream>>>(xn16, wvT + (size_t)l*262144,
        nullptr, nullptr, nullptr, vTb,
        isxl ? out_xlv + (size_t)xli*1048576 : nullptr, 4096,512,512);

    k_attn_win<<<dim3(16,8,4),256,0,stream>>>(
        q16, k16, vTb,
        isxl ? xlk16 + (size_t)src*1048576 : k16,
        isxl ? xlvT  + (size_t)src*1048576 : vTb,
        isxl ? 1 : 0, ao16, scale, table);

    k_gemmh64<1,0,0,0><<<dim3(64,4),256,0,stream>>>(ao16, woT + (size_t)l*262144,
        nullptr, hstate, nullptr, nullptr, nullptr, 4096,512,512);
    if (l==3){
      for (int nb=0;nb<2;nb++){
        k_ln<<<2048,256,0,stream>>>(states_cur, state_norm_g, sn16);
        k_gemmqk<0><<<dim3(16,5),256,0,stream>>>(sn16, wsqkvh,
            sq16, 512, 512, skv16, 128, nullptr, nullptr, nullptr, 0, 2048, 640, 512);
        k_vtrans16<<<dim3(8,1,4),256,0,stream>>>(skv16 + 64, svT, 65536L, 128, 32768L, 512);
        k_gemmqk<1><<<dim3(16,4),256,0,stream>>>(xn16, wq2sh,
            q2s16, 512, 512, nullptr, 0, nullptr, nullptr, nullptr, nb, 2048, 512, 512);
        k_attn_rec<<<dim3(16,8,4),256,0,stream>>>(
            q2s16, sq16, skv16, svT,
            k16 + (size_t)nb*262144, vTb + (size_t)nb*512,
            ts16 + (size_t)nb*262144, sa16);
        k_gemmh64<0,2,0,0><<<dim3(32,4),256,0,stream>>>(sa16, wstoutT, ema_beta,
            states_cur, nullptr, nullptr, nullptr, 2048,512,512);
      }
      k_gemmh64<1,0,0,0><<<dim3(64,4),256,0,stream>>>(ts16, wostT, nullptr,
          hstate, nullptr, nullptr, nullptr, 4096,512,512);
    }
    k_ln<<<4096,256,0,stream>>>(hstate, ff_g + l*512, xn16);
    k_gemmh<0,1,1><<<dim3(32,16),256,0,stream>>>(xn16, ffw1T + (size_t)l*1048576, ff_b1 + l*2048, nullptr, ff1_16, 4096,2048,512);
    k_gemmh64<1,0,0,0><<<dim3(64,4),256,0,stream>>>(ff1_16, ffw2T + (size_t)l*1048576, ff_b2 + l*512, hstate, nullptr, nullptr, nullptr, 4096,512,2048);
  }
  k_ln<<<4096,256,0,stream>>>(hstate, final_g, xn16);
  k_gemmh<0,0,0><<<dim3(32,157),256,0,stream>>>(xn16, wlogT, nullptr, out, nullptr, 4096,20000,512);
  k_copy<<<4096, 256, 0, stream>>>(out_states, states_cur, 1048576);
}

// Round 20
// 1473.705 us; speedup vs baseline: 1.0195x; 1.0195x over previous
//
#include <hip/hip_runtime.h>
#include <math.h>

// B=4 N=1024 V=20000 D=512 H=8 DH=64 W=512 NB=2 NS=512 FF=2048

typedef __attribute__((ext_vector_type(8))) _Float16 f16x8;
typedef __attribute__((ext_vector_type(4))) float f32x4;

__device__ __forceinline__ ushort f2h(float f){
  _Float16 h = (_Float16)f;
  return *reinterpret_cast<ushort*>(&h);
}
__device__ __forceinline__ uint pkh2(float a, float b){
  return (uint)f2h(a) | ((uint)f2h(b)<<16);
}

// ---------------- mega weight prep: 12 transposes in one launch ----------------
struct PrepDescs {
  const float* src[12];
  ushort*      dst[12];
  int K[12], N[12], nx[12], ny[12], cnt[12];
  long zs[12];
};

__global__ __launch_bounds__(256)
void k_prep_all(PrepDescs pd){
  __shared__ float tile[32][33];
  int bid = blockIdx.x, i = 0;
  while (i < 11 && bid >= pd.cnt[i]){ bid -= pd.cnt[i]; i++; }
  const int K = pd.K[i], N = pd.N[i], nx = pd.nx[i];
  const int z = bid/(nx*pd.ny[i]);
  const int rem = bid - z*nx*pd.ny[i];
  const int tyy = rem/nx, txx = rem - tyy*nx;
  const float* src = pd.src[i] + (size_t)z*K*N;
  ushort* dh = pd.dst[i] + (size_t)z*pd.zs[i];
  const int n0 = txx*32, k0 = tyy*32;
  const int tx = threadIdx.x&31, ty = threadIdx.x>>5;
#pragma unroll
  for (int u=0;u<4;u++){
    int kk = k0 + ty + u*8, nn = n0 + tx;
    tile[ty+u*8][tx] = (nn < N) ? src[(size_t)kk*N + nn] : 0.f;
  }
  __syncthreads();
#pragma unroll
  for (int u=0;u<4;u++){
    int nn = n0 + ty + u*8, kk = k0 + tx;
    dh[(size_t)nn*K + kk] = f2h(tile[tx][ty+u*8]);
  }
}

// ---------------- V transpose (startup xl mem only) ----------------
__global__ __launch_bounds__(256)
void k_vtrans(const float* __restrict__ src, ushort* __restrict__ dst,
              long sB, int sR, int sMH, long dB, long dH, int NK){
  __shared__ float tile[64][65];
  int kc = blockIdx.x, h = blockIdx.y, b = blockIdx.z;
  int t = threadIdx.x;
  int key = t>>2, doff = (t&3)*16;
  const float* sp = src + (size_t)b*sB + (size_t)(kc*64+key)*sR + (sMH? h*64:0) + doff;
#pragma unroll
  for (int u=0;u<4;u++){
    float4 v = *reinterpret_cast<const float4*>(sp + u*4);
    tile[key][doff+u*4+0]=v.x; tile[key][doff+u*4+1]=v.y;
    tile[key][doff+u*4+2]=v.z; tile[key][doff+u*4+3]=v.w;
  }
  __syncthreads();
  int d = t>>2, kf = (t&3)*16;
  ushort* dp = dst + (size_t)b*dB + (size_t)h*dH + (size_t)d*NK + kc*64 + kf;
  ushort tmp[16];
#pragma unroll
  for (int u=0;u<16;u++) tmp[u] = f2h(tile[kf+u][d]);
  uint4 o0 = make_uint4((uint)tmp[0]|((uint)tmp[1]<<16), (uint)tmp[2]|((uint)tmp[3]<<16),
                        (uint)tmp[4]|((uint)tmp[5]<<16), (uint)tmp[6]|((uint)tmp[7]<<16));
  uint4 o1 = make_uint4((uint)tmp[8]|((uint)tmp[9]<<16), (uint)tmp[10]|((uint)tmp[11]<<16),
                        (uint)tmp[12]|((uint)tmp[13]<<16),(uint)tmp[14]|((uint)tmp[15]<<16));
  *reinterpret_cast<uint4*>(dp)   = o0;
  *reinterpret_cast<uint4*>(dp+8) = o1;
}

// fp16 -> fp16 transpose (for skv16 V half)
__global__ __launch_bounds__(256)
void k_vtrans16(const ushort* __restrict__ src, ushort* __restrict__ dst,
                long sB, int sR, long dB, int NK){
  __shared__ ushort tile[64][72];
  int kc = blockIdx.x, b = blockIdx.z;
  int t = threadIdx.x;
  int key = t>>2, doff = (t&3)*16;
  const ushort* sp = src + (size_t)b*sB + (size_t)(kc*64+key)*sR + doff;
  *reinterpret_cast<uint4*>(&tile[key][doff])   = *reinterpret_cast<const uint4*>(sp);
  *reinterpret_cast<uint4*>(&tile[key][doff+8]) = *reinterpret_cast<const uint4*>(sp+8);
  __syncthreads();
  int d = t>>2, kf = (t&3)*16;
  ushort* dp = dst + (size_t)b*dB + (size_t)d*NK + kc*64 + kf;
  ushort tmp[16];
#pragma unroll
  for (int u=0;u<16;u++) tmp[u] = tile[kf+u][d];
  uint4 o0 = make_uint4((uint)tmp[0]|((uint)tmp[1]<<16), (uint)tmp[2]|((uint)tmp[3]<<16),
                        (uint)tmp[4]|((uint)tmp[5]<<16), (uint)tmp[6]|((uint)tmp[7]<<16));
  uint4 o1 = make_uint4((uint)tmp[8]|((uint)tmp[9]<<16), (uint)tmp[10]|((uint)tmp[11]<<16),
                        (uint)tmp[12]|((uint)tmp[13]<<16),(uint)tmp[14]|((uint)tmp[15]<<16));
  *reinterpret_cast<uint4*>(dp)   = o0;
  *reinterpret_cast<uint4*>(dp+8) = o1;
}

__global__ void k_cvt(ushort* __restrict__ dst, const float* __restrict__ src, int n2){
  int idx = blockIdx.x*blockDim.x + threadIdx.x;
  if (idx >= n2) return;
  reinterpret_cast<uint*>(dst)[idx] = pkh2(src[2*idx], src[2*idx+1]);
}

// ---------------- embed / postable ----------------
__global__ void k_embed(const int* __restrict__ x, const float* __restrict__ emb,
                        float* __restrict__ h, int total4){
  int idx = blockIdx.x*blockDim.x + threadIdx.x;
  if (idx >= total4) return;
  int row = idx >> 7;
  int c4  = idx & 127;
  int tok = x[row];
  reinterpret_cast<float4*>(h)[idx] =
      reinterpret_cast<const float4*>(emb)[(size_t)tok*128 + c4];
}

__global__ void k_postable(const float* __restrict__ w1, const float* __restrict__ b1,
                           const float* __restrict__ w2, const float* __restrict__ b2,
                           const float* __restrict__ w3, const float* __restrict__ b3,
                           float* __restrict__ table){
  __shared__ float h1[128];
  __shared__ float h2[128];
  int d = blockIdx.x, t = threadIdx.x;
  float a = (float)d * w1[t] + b1[t];
  h1[t] = a / (1.f + __expf(-a));
  __syncthreads();
  float acc = b2[t];
  for (int p=0;p<128;p++) acc += h1[p]*w2[p*128+t];
  h2[t] = acc / (1.f + __expf(-acc));
  __syncthreads();
  if (t < 8){
    float acc2 = b3[t];
    for (int p=0;p<128;p++) acc2 += h2[p]*w3[p*8+t];
    table[d*8+t] = acc2;
  }
}

// ---------------- layernorm -> fp16 ----------------
__global__ void k_ln(const float* __restrict__ x, const float* __restrict__ g,
                     ushort* __restrict__ y16){
  int row = blockIdx.x;
  int t = threadIdx.x;
  float2 v = reinterpret_cast<const float2*>(x + (size_t)row*512)[t];
  float s = v.x+v.y, ss = v.x*v.x+v.y*v.y;
  for (int o=32;o;o>>=1){ s += __shfl_down(s,o); ss += __shfl_down(ss,o); }
  __shared__ float ls[4], lss[4];
  __shared__ float smu, srs;
  int wid = t>>6;
  if ((t&63)==0){ ls[wid]=s; lss[wid]=ss; }
  __syncthreads();
  if (t==0){
    float S=ls[0]+ls[1]+ls[2]+ls[3], SS=lss[0]+lss[1]+lss[2]+lss[3];
    float mu = S*(1.f/512.f);
    float var = SS*(1.f/512.f) - mu*mu;
    smu = mu; srs = rsqrtf(var + 1e-5f);
  }
  __syncthreads();
  float mu=smu, rs=srs;
  float2 gg = reinterpret_cast<const float2*>(g)[t];
  float ya = (v.x-mu)*rs*gg.x, yb = (v.y-mu)*rs*gg.y;
  *reinterpret_cast<uint*>(&y16[(size_t)row*512 + 2*t]) = pkh2(ya, yb);
}

__device__ __forceinline__ float geluf(float x){
  float u = 1.5957691216f*(x + 0.044715f*x*x*x);
  return x / (1.f + __expf(-u));
}

// ---------------- fp16 MFMA GEMM 128x128 (FF1, logits) -----------------------
// reg-staged [128][68] LDS (proven); XCD-aware bijective block swizzle
// (requires gridDim.x*gridDim.y % 8 == 0 — holds for both call sites).
template<int ACC, int EPI, int OUT16>
__global__ __launch_bounds__(256)
void k_gemmh(const ushort* __restrict__ A, const ushort* __restrict__ Bt,
             const float* __restrict__ bias, float* __restrict__ C,
             ushort* __restrict__ C16, int M, int N, int K){
  __shared__ ushort As[128][68];
  __shared__ ushort Bs[128][68];
  const int t = threadIdx.x;
  // XCD swizzle: contiguous run of nwg/8 blocks per XCD
  const int lid = blockIdx.y*gridDim.x + blockIdx.x;
  const int cpx = (gridDim.x*gridDim.y) >> 3;
  const int swz = (lid&7)*cpx + (lid>>3);
  const int m0 = (swz % gridDim.x)*128, n0 = (swz / gridDim.x)*128;
  const int w = t>>6, lane = t&63;
  const int wm = (w>>1)*64, wn = (w&1)*64;
  const int fr = lane&15, fg = lane>>4;
  const int srow = t>>1, sko = (t&1)*32;

  f32x4 acc[4][4];
#pragma unroll
  for (int i=0;i<4;i++)
#pragma unroll
    for (int j=0;j<4;j++){ acc[i][j][0]=0.f; acc[i][j][1]=0.f; acc[i][j][2]=0.f; acc[i][j][3]=0.f; }

  const ushort* ap = A  + (size_t)(m0+srow)*K + sko;
  const ushort* bp = Bt + (size_t)(n0+srow)*K + sko;

  for (int k0=0; k0<K; k0+=64){
    uint4 av[4], bv[4];
#pragma unroll
    for (int u=0;u<4;u++){
      av[u] = *reinterpret_cast<const uint4*>(ap + k0 + u*8);
      bv[u] = *reinterpret_cast<const uint4*>(bp + k0 + u*8);
    }
#pragma unroll
    for (int u=0;u<4;u++){
      *reinterpret_cast<uint4*>(&As[srow][sko+u*8]) = av[u];
      *reinterpret_cast<uint4*>(&Bs[srow][sko+u*8]) = bv[u];
    }
    __syncthreads();
#pragma unroll
    for (int kk=0;kk<2;kk++){
      f16x8 af[4], bf[4];
#pragma unroll
      for (int mi=0;mi<4;mi++)
        af[mi] = *reinterpret_cast<const f16x8*>(&As[wm+mi*16+fr][kk*32+fg*8]);
#pragma unroll
      for (int nj=0;nj<4;nj++)
        bf[nj] = *reinterpret_cast<const f16x8*>(&Bs[wn+nj*16+fr][kk*32+fg*8]);
#pragma unroll
      for (int mi=0;mi<4;mi++)
#pragma unroll
        for (int nj=0;nj<4;nj++)
          acc[mi][nj] = __builtin_amdgcn_mfma_f32_16x16x32_f16(af[mi], bf[nj], acc[mi][nj], 0,0,0);
    }
    __syncthreads();
  }
#pragma unroll
  for (int mi=0;mi<4;mi++){
#pragma unroll
    for (int r=0;r<4;r++){
      int row = m0 + wm + mi*16 + fg*4 + r;
#pragma unroll
      for (int nj=0;nj<4;nj++){
        int col = n0 + wn + nj*16 + fr;
        if (col < N){
          float val = acc[mi][nj][r];
          if (bias) val += bias[col];
          if (EPI==1) val = geluf(val);
          if (OUT16){
            C16[(size_t)row*N + col] = f2h(val);
          } else {
            if (ACC) C[(size_t)row*N + col] += val; else C[(size_t)row*N + col] = val;
          }
        }
      }
    }
  }
}

// ---------------- fp16 MFMA GEMM 128x128 with split out + rms + remap --------
template<int REMAP>
__global__ __launch_bounds__(256)
void k_gemmqk(const ushort* __restrict__ A, const ushort* __restrict__ Bt,
              ushort* __restrict__ C1h, int ld1, int N1,
              ushort* __restrict__ C2h, int ld2,
              const float* __restrict__ qsc, const float* __restrict__ ksc,
              float* __restrict__ xlk,
              int nb, int M, int N, int K){
  __shared__ ushort As[128][68];
  __shared__ ushort Bs[128][68];
  const int t = threadIdx.x;
  const int m0 = blockIdx.x*128, n0 = blockIdx.y*128;
  const int w = t>>6, lane = t&63;
  const int wm = (w>>1)*64, wn = (w&1)*64;
  const int fr = lane&15, fg = lane>>4;
  const int srow = t>>1, sko = (t&1)*32;

  f32x4 acc[4][4];
#pragma unroll
  for (int i=0;i<4;i++)
#pragma unroll
    for (int j=0;j<4;j++){ acc[i][j][0]=0.f; acc[i][j][1]=0.f; acc[i][j][2]=0.f; acc[i][j][3]=0.f; }

  int mrow = m0 + srow;
  int arow = REMAP ? ((mrow>>9)*1024 + nb*512 + (mrow&511)) : mrow;
  const ushort* ap = A  + (size_t)arow*K + sko;
  const ushort* bp = Bt + (size_t)(n0+srow)*K + sko;

  for (int k0=0; k0<K; k0+=64){
    uint4 av[4], bv[4];
#pragma unroll
    for (int u=0;u<4;u++){
      av[u] = *reinterpret_cast<const uint4*>(ap + k0 + u*8);
      bv[u] = *reinterpret_cast<const uint4*>(bp + k0 + u*8);
    }
#pragma unroll
    for (int u=0;u<4;u++){
      *reinterpret_cast<uint4*>(&As[srow][sko+u*8]) = av[u];
      *reinterpret_cast<uint4*>(&Bs[srow][sko+u*8]) = bv[u];
    }
    __syncthreads();
#pragma unroll
    for (int kk=0;kk<2;kk++){
      f16x8 af[4], bf[4];
#pragma unroll
      for (int mi=0;mi<4;mi++)
        af[mi] = *reinterpret_cast<const f16x8*>(&As[wm+mi*16+fr][kk*32+fg*8]);
#pragma unroll
      for (int nj=0;nj<4;nj++)
        bf[nj] = *reinterpret_cast<const f16x8*>(&Bs[wn+nj*16+fr][kk*32+fg*8]);
#pragma unroll
      for (int mi=0;mi<4;mi++)
#pragma unroll
        for (int nj=0;nj<4;nj++)
          acc[mi][nj] = __builtin_amdgcn_mfma_f32_16x16x32_f16(af[mi], bf[nj], acc[mi][nj], 0,0,0);
    }
    __syncthreads();
  }
#pragma unroll
  for (int mi=0;mi<4;mi++){
#pragma unroll
    for (int r=0;r<4;r++){
      int row = m0 + wm + mi*16 + fg*4 + r;
      float vals[4];
#pragma unroll
      for (int nj=0;nj<4;nj++) vals[nj] = acc[mi][nj][r];
      if (qsc){
        float ss = vals[0]*vals[0]+vals[1]*vals[1]+vals[2]*vals[2]+vals[3]*vals[3];
        ss += __shfl_xor(ss,1);
        ss += __shfl_xor(ss,2);
        ss += __shfl_xor(ss,4);
        ss += __shfl_xor(ss,8);
        float rs = rsqrtf(ss + 1e-12f);
        const float* sc = ((n0+wn) < N1) ? qsc : ksc;
#pragma unroll
        for (int nj=0;nj<4;nj++) vals[nj] = vals[nj]*rs*sc[nj*16+fr];
      }
#pragma unroll
      for (int nj=0;nj<4;nj++){
        int col = n0 + wn + nj*16 + fr;
        float val = vals[nj];
        if (col < N1){
          C1h[(size_t)row*ld1 + col] = f2h(val);
        } else if (col < N){
          if (C2h) C2h[(size_t)row*ld2 + (col-N1)] = f2h(val);
          if (xlk && (row&1023) >= 512)
            xlk[((size_t)(row>>10)*512 + (row&1023) - 512)*512 + (col-N1)] = val;
        }
      }
    }
  }
}

// ---------------- fp16 MFMA GEMM 64x128 (N=512 class) ------------------------
// EPI: 0 none, 1 gelu, 2 ema. VT=1: fp16 transposed vT + optional fp32 xlv.
template<int ACC, int EPI, int OUT16, int VT>
__global__ __launch_bounds__(256)
void k_gemmh64(const ushort* __restrict__ A, const ushort* __restrict__ Bt,
               const float* __restrict__ bias, float* __restrict__ C,
               ushort* __restrict__ C16, ushort* __restrict__ vT,
               float* __restrict__ xlv, int M, int N, int K){
  __shared__ ushort As[64][68];
  __shared__ ushort Bs[128][68];
  const int t = threadIdx.x;
  const int m0 = blockIdx.x*64, n0 = blockIdx.y*128;
  const int w = t>>6, lane = t&63;
  const int wm = (w>>1)*32, wn = (w&1)*64;
  const int fr = lane&15, fg = lane>>4;
  const int srowA = t>>2, skoA = (t&3)*16;
  const int srowB = t>>1, skoB = (t&1)*32;

  f32x4 acc[2][4];
#pragma unroll
  for (int i=0;i<2;i++)
#pragma unroll
    for (int j=0;j<4;j++){ acc[i][j][0]=0.f; acc[i][j][1]=0.f; acc[i][j][2]=0.f; acc[i][j][3]=0.f; }

  const ushort* ap = A  + (size_t)(m0+srowA)*K + skoA;
  const ushort* bp = Bt + (size_t)(n0+srowB)*K + skoB;

  for (int k0=0; k0<K; k0+=64){
    uint4 a0 = *reinterpret_cast<const uint4*>(ap + k0);
    uint4 a1 = *reinterpret_cast<const uint4*>(ap + k0 + 8);
    uint4 b0 = *reinterpret_cast<const uint4*>(bp + k0);
    uint4 b1 = *reinterpret_cast<const uint4*>(bp + k0 + 8);
    uint4 b2 = *reinterpret_cast<const uint4*>(bp + k0 + 16);
    uint4 b3 = *reinterpret_cast<const uint4*>(bp + k0 + 24);
    *reinterpret_cast<uint4*>(&As[srowA][skoA])    = a0;
    *reinterpret_cast<uint4*>(&As[srowA][skoA+8])  = a1;
    *reinterpret_cast<uint4*>(&Bs[srowB][skoB])    = b0;
    *reinterpret_cast<uint4*>(&Bs[srowB][skoB+8])  = b1;
    *reinterpret_cast<uint4*>(&Bs[srowB][skoB+16]) = b2;
    *reinterpret_cast<uint4*>(&Bs[srowB][skoB+24]) = b3;
    __syncthreads();
#pragma unroll
    for (int kk=0;kk<2;kk++){
      f16x8 af[2], bf[4];
#pragma unroll
      for (int mi=0;mi<2;mi++)
        af[mi] = *reinterpret_cast<const f16x8*>(&As[wm+mi*16+fr][kk*32+fg*8]);
#pragma unroll
      for (int nj=0;nj<4;nj++)
        bf[nj] = *reinterpret_cast<const f16x8*>(&Bs[wn+nj*16+fr][kk*32+fg*8]);
#pragma unroll
      for (int mi=0;mi<2;mi++)
#pragma unroll
        for (int nj=0;nj<4;nj++)
          acc[mi][nj] = __builtin_amdgcn_mfma_f32_16x16x32_f16(af[mi], bf[nj], acc[mi][nj], 0,0,0);
    }
    __syncthreads();
  }
#pragma unroll
  for (int mi=0;mi<2;mi++){
#pragma unroll
    for (int r=0;r<4;r++){
      int row = m0 + wm + mi*16 + fg*4 + r;
#pragma unroll
      for (int nj=0;nj<4;nj++){
        int col = n0 + wn + nj*16 + fr;
        if (col < N){
          float val = acc[mi][nj][r];
          if (EPI==2){
            size_t idx = (size_t)row*N + col;
            float old = C[idx];
            float dec = 1.f/(1.f+__expf(-bias[col]));
            C[idx] = dec*old + (1.f-dec)*val;
          } else {
            if (bias) val += bias[col];
            if (EPI==1) val = geluf(val);
            if (OUT16){
              if (C16) C16[(size_t)row*N + col] = f2h(val);
            } else if (C){
              if (ACC) C[(size_t)row*N + col] += val; else C[(size_t)row*N + col] = val;
            }
            if (VT && xlv && (row&1023) >= 512)
              xlv[((size_t)(row>>10)*512 + (row&1023) - 512)*512 + col] = val;
          }
        }
      }
    }
  }
  if (VT){
#pragma unroll
    for (int mi=0;mi<2;mi++)
#pragma unroll
      for (int r=0;r<4;r++)
#pragma unroll
        for (int nj=0;nj<4;nj++)
          Bs[wn+nj*16+fr][wm+mi*16+fg*4+r] = f2h(acc[mi][nj][r]);
    __syncthreads();
    int c = t>>1, half = t&1;
    int hh = (n0+c)>>6, dd = (n0+c)&63;
    int bb = m0>>10, posb = m0&1023;
    ushort* dp = vT + (size_t)bb*524288 + (size_t)hh*65536 + (size_t)dd*1024 + posb + half*32;
#pragma unroll
    for (int u=0;u<4;u++)
      *reinterpret_cast<uint4*>(dp + u*8) = *reinterpret_cast<const uint4*>(&Bs[c][half*32 + u*8]);
  }
}

// ---------------- merged windowed MFMA flash attention -----------------------
__global__ __launch_bounds__(256)
void k_attn_win(const ushort* __restrict__ q16, const ushort* __restrict__ k16,
                const ushort* __restrict__ vTb,
                const ushort* __restrict__ xlK, const ushort* __restrict__ xlVT,
                int isxl, ushort* __restrict__ O, float scale,
                const float* __restrict__ table){
  __shared__ ushort Qs[64][72];
  __shared__ ushort Ks[64][72];
  __shared__ ushort Vs[64][72];
  __shared__ ushort Pw[4][16][72];
  __shared__ float tcol[512];
  const int b = blockIdx.z, h = blockIdx.y;
  const int nb = blockIdx.x>>3, qt = blockIdx.x&7;
  const int t = threadIdx.x, w = t>>6, lane = t&63;
  const int fr = lane&15, fg = lane>>4;
  tcol[t]     = table[t*8 + h];
  tcol[t+256] = table[(t+256)*8 + h];

  const ushort* Q  = q16 + (size_t)nb*262144;
  const ushort* K1 = k16 + (size_t)nb*262144;
  const ushort* V1 = vTb + (size_t)nb*512;
  ushort* Op = O + (size_t)nb*262144;
  const int has_mem = (nb==1) || isxl;
  const ushort* K0; long k0B; const ushort* V0; long vt0B, vt0H; int vt0D;
  if (nb==1){ K0=k16; k0B=524288; V0=vTb; vt0B=524288; vt0H=65536; vt0D=1024; }
  else if (isxl){ K0=xlK; k0B=262144; V0=xlVT; vt0B=262144; vt0H=32768; vt0D=512; }
  else { K0=k16; k0B=524288; V0=vTb; vt0B=524288; vt0H=65536; vt0D=1024; }

  {
    int qrow = t>>2, doff = (t&3)*16;
    const ushort* qp = Q + (size_t)b*524288 + (size_t)(qt*64+qrow)*512 + h*64 + doff;
    *reinterpret_cast<uint4*>(&Qs[qrow][doff])   = *reinterpret_cast<const uint4*>(qp);
    *reinterpret_cast<uint4*>(&Qs[qrow][doff+8]) = *reinterpret_cast<const uint4*>(qp+8);
  }
  __syncthreads();
  f16x8 aq[2];
  aq[0] = *reinterpret_cast<const f16x8*>(&Qs[w*16+fr][fg*8]);
  aq[1] = *reinterpret_cast<const f16x8*>(&Qs[w*16+fr][32+fg*8]);

  f32x4 so[4];
#pragma unroll
  for (int dt=0;dt<4;dt++){ so[dt][0]=0.f; so[dt][1]=0.f; so[dt][2]=0.f; so[dt][3]=0.f; }
  float m[4] = {-1e30f,-1e30f,-1e30f,-1e30f};
  float lsum[4] = {0.f,0.f,0.f,0.f};

  const int srow = t>>2, sdo = (t&3)*16;
  const int vd = t>>2,   vkf = (t&3)*16;

  int jt0 = has_mem ? qt : 8;
  int jt1 = qt + 8; if (jt1 > 15) jt1 = 15;

  for (int jt=jt0; jt<=jt1; jt++){
    {
      int key = jt*64 + srow;
      const ushort* kp;
      if (key < 512) kp = K0 + (size_t)b*k0B + (size_t)key*512 + h*64 + sdo;
      else           kp = K1 + (size_t)b*524288 + (size_t)(key-512)*512 + h*64 + sdo;
      *reinterpret_cast<uint4*>(&Ks[srow][sdo])   = *reinterpret_cast<const uint4*>(kp);
      *reinterpret_cast<uint4*>(&Ks[srow][sdo+8]) = *reinterpret_cast<const uint4*>(kp+8);
    }
    {
      const ushort* vp;
      if (jt*64 < 512) vp = V0 + (size_t)b*vt0B + (size_t)h*vt0H + (size_t)vd*vt0D + jt*64 + vkf;
      else             vp = V1 + (size_t)b*524288 + (size_t)h*65536 + (size_t)vd*1024 + (jt*64-512) + vkf;
      *reinterpret_cast<uint4*>(&Vs[vd][vkf])   = *reinterpret_cast<const uint4*>(vp);
      *reinterpret_cast<uint4*>(&Vs[vd][vkf+8]) = *reinterpret_cast<const uint4*>(vp+8);
    }
    __syncthreads();
    f32x4 sacc[4];
#pragma unroll
    for (int kt=0;kt<4;kt++){ sacc[kt][0]=0.f; sacc[kt][1]=0.f; sacc[kt][2]=0.f; sacc[kt][3]=0.f; }
#pragma unroll
    for (int ks=0;ks<2;ks++){
#pragma unroll
      for (int kt=0;kt<4;kt++){
        f16x8 bf = *reinterpret_cast<const f16x8*>(&Ks[kt*16+fr][ks*32+fg*8]);
        sacc[kt] = __builtin_amdgcn_mfma_f32_16x16x32_f16(aq[ks], bf, sacc[kt], 0,0,0);
      }
    }
#pragma unroll
    for (int r=0;r<4;r++){
      float sv[4];
      int ia = qt*64 + w*16 + fg*4 + r;
#pragma unroll
      for (int kt=0;kt<4;kt++){
        float s = sacc[kt][r]*scale;
        int jg = jt*64 + kt*16 + fr;
        bool valid = (jg > ia) && (jg <= ia+512) && (has_mem || jg >= 512);
        sv[kt] = valid ? s + tcol[ia+512-jg] : -1e9f;
      }
      float tm = fmaxf(fmaxf(sv[0],sv[1]), fmaxf(sv[2],sv[3]));
      tm = fmaxf(tm, __shfl_xor(tm,1));
      tm = fmaxf(tm, __shfl_xor(tm,2));
      tm = fmaxf(tm, __shfl_xor(tm,4));
      tm = fmaxf(tm, __shfl_xor(tm,8));
      float mn = fmaxf(m[r], tm);
      float c = __expf(m[r]-mn);
      m[r] = mn;
      float ps = 0.f;
#pragma unroll
      for (int kt=0;kt<4;kt++){
        float pp = (sv[kt] <= -1e8f) ? 0.f : __expf(sv[kt]-mn);
        ps += pp;
        Pw[w][fg*4+r][kt*16+fr] = f2h(pp);
      }
      ps += __shfl_xor(ps,1);
      ps += __shfl_xor(ps,2);
      ps += __shfl_xor(ps,4);
      ps += __shfl_xor(ps,8);
      lsum[r] = lsum[r]*c + ps;
#pragma unroll
      for (int dt=0;dt<4;dt++) so[dt][r] *= c;
    }
#pragma unroll
    for (int ks=0;ks<2;ks++){
      f16x8 pa = *reinterpret_cast<const f16x8*>(&Pw[w][fr][ks*32+fg*8]);
#pragma unroll
      for (int dt=0;dt<4;dt++){
        f16x8 bv = *reinterpret_cast<const f16x8*>(&Vs[dt*16+fr][ks*32+fg*8]);
        so[dt] = __builtin_amdgcn_mfma_f32_16x16x32_f16(pa, bv, so[dt], 0,0,0);
      }
    }
    __syncthreads();
  }
#pragma unroll
  for (int r=0;r<4;r++){
    int row = qt*64 + w*16 + fg*4 + r;
    float inv = 1.f / lsum[r];
    ushort* op = Op + (size_t)b*524288 + (size_t)row*512 + h*64;
#pragma unroll
    for (int dt=0;dt<4;dt++)
      op[dt*16+fr] = f2h(so[dt][r]*inv);
  }
}

// ---------------- merged rec-layer attentions ----------------
__global__ __launch_bounds__(256)
void k_attn_rec(const ushort* __restrict__ q2s, const ushort* __restrict__ sq,
                const ushort* __restrict__ skv, const ushort* __restrict__ svT,
                const ushort* __restrict__ kblk, const ushort* __restrict__ vblk,
                ushort* __restrict__ ts, ushort* __restrict__ sa){
  __shared__ ushort Qs[64][72];
  __shared__ ushort Ks[64][72];
  __shared__ ushort Vs[64][72];
  __shared__ ushort Pw[4][16][72];
  const int b = blockIdx.z, h = blockIdx.y;
  const int task = blockIdx.x>>3, qt = blockIdx.x&7;
  const int t = threadIdx.x, w = t>>6, lane = t&63;
  const int fr = lane&15, fg = lane>>4;

  const ushort* Q; const ushort* K1; int k1R, k1H;
  const ushort* VT1; long vt1B, vt1H; int vt1D;
  int nt; ushort* O; long oB;
  if (task==0){
    Q=q2s; K1=skv; k1R=128; k1H=0;
    VT1=svT; vt1B=32768; vt1H=0; vt1D=512;
    nt=8; O=ts; oB=524288;
  } else {
    Q=sq; K1=kblk; k1R=512; k1H=1;
    VT1=vblk; vt1B=524288; vt1H=65536; vt1D=1024;
    nt=16; O=sa; oB=262144;
  }

  {
    int qrow = t>>2, doff = (t&3)*16;
    const ushort* qp = Q + (size_t)b*262144 + (size_t)(qt*64+qrow)*512 + h*64 + doff;
    *reinterpret_cast<uint4*>(&Qs[qrow][doff])   = *reinterpret_cast<const uint4*>(qp);
    *reinterpret_cast<uint4*>(&Qs[qrow][doff+8]) = *reinterpret_cast<const uint4*>(qp+8);
  }
  __syncthreads();
  f16x8 aq[2];
  aq[0] = *reinterpret_cast<const f16x8*>(&Qs[w*16+fr][fg*8]);
  aq[1] = *reinterpret_cast<const f16x8*>(&Qs[w*16+fr][32+fg*8]);

  f32x4 so[4];
#pragma unroll
  for (int dt=0;dt<4;dt++){ so[dt][0]=0.f; so[dt][1]=0.f; so[dt][2]=0.f; so[dt][3]=0.f; }
  float m[4] = {-1e30f,-1e30f,-1e30f,-1e30f};
  float lsum[4] = {0.f,0.f,0.f,0.f};

  const int srow = t>>2, sdo = (t&3)*16;
  const int vd = t>>2,   vkf = (t&3)*16;

  for (int jt=0; jt<nt; jt++){
    {
      int key = jt*64 + srow;
      const ushort* kp;
      if (key < 512) kp = skv + (size_t)b*65536 + (size_t)key*128 + sdo;
      else           kp = K1 + (size_t)b*524288 + (size_t)(key-512)*k1R + (k1H? h*64:0) + sdo;
      *reinterpret_cast<uint4*>(&Ks[srow][sdo])   = *reinterpret_cast<const uint4*>(kp);
      *reinterpret_cast<uint4*>(&Ks[srow][sdo+8]) = *reinterpret_cast<const uint4*>(kp+8);
    }
    {
      const ushort* vp;
      if (jt*64 < 512) vp = svT + (size_t)b*32768 + (size_t)vd*512 + jt*64 + vkf;
      else             vp = VT1 + (size_t)b*vt1B + (size_t)h*vt1H + (size_t)vd*vt1D + (jt*64-512) + vkf;
      *reinterpret_cast<uint4*>(&Vs[vd][vkf])   = *reinterpret_cast<const uint4*>(vp);
      *reinterpret_cast<uint4*>(&Vs[vd][vkf+8]) = *reinterpret_cast<const uint4*>(vp+8);
    }
    __syncthreads();
    f32x4 sacc[4];
#pragma unroll
    for (int kt=0;kt<4;kt++){ sacc[kt][0]=0.f; sacc[kt][1]=0.f; sacc[kt][2]=0.f; sacc[kt][3]=0.f; }
#pragma unroll
    for (int ks=0;ks<2;ks++){
#pragma unroll
      for (int kt=0;kt<4;kt++){
        f16x8 bf = *reinterpret_cast<const f16x8*>(&Ks[kt*16+fr][ks*32+fg*8]);
        sacc[kt] = __builtin_amdgcn_mfma_f32_16x16x32_f16(aq[ks], bf, sacc[kt], 0,0,0);
      }
    }
#pragma unroll
    for (int r=0;r<4;r++){
      float sv[4];
#pragma unroll
      for (int kt=0;kt<4;kt++) sv[kt] = sacc[kt][r]*0.125f;
      float tm = fmaxf(fmaxf(sv[0],sv[1]), fmaxf(sv[2],sv[3]));
      tm = fmaxf(tm, __shfl_xor(tm,1));
      tm = fmaxf(tm, __shfl_xor(tm,2));
      tm = fmaxf(tm, __shfl_xor(tm,4));
      tm = fmaxf(tm, __shfl_xor(tm,8));
      float mn = fmaxf(m[r], tm);
      float c = __expf(m[r]-mn);
      m[r] = mn;
      float ps = 0.f;
#pragma unroll
      for (int kt=0;kt<4;kt++){
        float pp = __expf(sv[kt]-mn);
        ps += pp;
        Pw[w][fg*4+r][kt*16+fr] = f2h(pp);
      }
      ps += __shfl_xor(ps,1);
      ps += __shfl_xor(ps,2);
      ps += __shfl_xor(ps,4);
      ps += __shfl_xor(ps,8);
      lsum[r] = lsum[r]*c + ps;
#pragma unroll
      for (int dt=0;dt<4;dt++) so[dt][r] *= c;
    }
#pragma unroll
    for (int ks=0;ks<2;ks++){
      f16x8 pa = *reinterpret_cast<const f16x8*>(&Pw[w][fr][ks*32+fg*8]);
#pragma unroll
      for (int dt=0;dt<4;dt++){
        f16x8 bv = *reinterpret_cast<const f16x8*>(&Vs[dt*16+fr][ks*32+fg*8]);
        so[dt] = __builtin_amdgcn_mfma_f32_16x16x32_f16(pa, bv, so[dt], 0,0,0);
      }
    }
    __syncthreads();
  }
#pragma unroll
  for (int r=0;r<4;r++){
    int row = qt*64 + w*16 + fg*4 + r;
    float inv = 1.f / lsum[r];
    ushort* op = O + (size_t)b*oB + (size_t)row*512 + h*64;
#pragma unroll
    for (int dt=0;dt<4;dt++)
      op[dt*16+fr] = f2h(so[dt][r]*inv);
  }
}

// ---------------- small utility kernels ----------------
__global__ void k_copy(float* __restrict__ dst, const float* __restrict__ src, int n){
  int idx = blockIdx.x*blockDim.x + threadIdx.x;
  if (idx < n) dst[idx] = src[idx];
}

// ---------------- launcher ----------------
extern "C" void kernel_launch(void* const* d_in, const int* in_sizes, int n_in,
                              void* d_out, int out_size, void* d_ws, size_t ws_size,
                              hipStream_t stream){
  // floats 12,599,296 B + ushorts 106,954,752 B = 119,554,048 B
  if (ws_size < (size_t)119554048) return;

  const int*   x        = (const int*)  d_in[0];
  const float* tok_emb  = (const float*)d_in[1];
  const float* pw1 = (const float*)d_in[2];
  const float* pb1 = (const float*)d_in[3];
  const float* pw2 = (const float*)d_in[4];
  const float* pb2 = (const float*)d_in[5];
  const float* pw3 = (const float*)d_in[6];
  const float* pb3 = (const float*)d_in[7];
  const float* ln_g = (const float*)d_in[8];
  const float* Wq = (const float*)d_in[9];
  const float* Wk = (const float*)d_in[10];
  const float* Wv = (const float*)d_in[11];
  const float* Wo = (const float*)d_in[12];
  const float* q_scale = (const float*)d_in[13];
  const float* k_scale = (const float*)d_in[14];
  const float* Wo_state = (const float*)d_in[15];
  const float* state_norm_g = (const float*)d_in[16];
  const float* Wq2s = (const float*)d_in[17];
  const float* Ws2q = (const float*)d_in[18];
  const float* Ws2kv = (const float*)d_in[19];
  const float* W_state_out = (const float*)d_in[20];
  const float* ema_beta = (const float*)d_in[21];
  const float* ff_g = (const float*)d_in[22];
  const float* ff_w1 = (const float*)d_in[23];
  const float* ff_b1 = (const float*)d_in[24];
  const float* ff_w2 = (const float*)d_in[25];
  const float* ff_b2 = (const float*)d_in[26];
  const float* final_g = (const float*)d_in[27];
  const float* W_logits = (const float*)d_in[28];
  const float* xl_mem_k = (const float*)d_in[29];
  const float* xl_mem_v = (const float*)d_in[30];
  const float* states_in = (const float*)d_in[31];

  float* out = (float*)d_out;
  float* out_xlk    = out + 81920000;
  float* out_xlv    = out + 84017152;
  float* out_states = out + 86114304;

  float* p = (float*)d_ws;
  float* hstate   = p; p += 2097152;
  float* states_cur = p; p += 1048576;
  float* table    = p; p += 4096;

  ushort* us = (ushort*)p;
  ushort* wqkh  = us; us += 3145728;   // [6][1024][512]: rows 0-511 q, 512-1023 k
  ushort* wvT   = us; us += 1572864;
  ushort* woT   = us; us += 1572864;
  ushort* ffw1T = us; us += 6291456;
  ushort* ffw2T = us; us += 6291456;
  ushort* wostT = us; us += 262144;
  ushort* wstoutT = us; us += 262144;
  ushort* wq2sh = us; us += 262144;
  ushort* wsqkvh = us; us += 327680;   // [640][512]: rows 0-511 Ws2q, 512-639 Ws2kv
  ushort* wlogT  = us; us += 10289152; // [20096][512]
  ushort* vTb   = us; us += 2097152;   // [b][h][64][1024]
  ushort* xlvT  = us; us += 2097152;   // [2][b][h][64][512]
  ushort* svT   = us; us += 131072;    // [b][64][512]
  ushort* xn16  = us; us += 2097152;
  ushort* ao16  = us; us += 2097152;
  ushort* ff1_16 = us; us += 8388608;  // [4096][2048] + rec aliases
  ushort* q16   = us; us += 2097152;
  ushort* k16   = us; us += 2097152;
  ushort* xlk16 = us; us += 2097152;   // [2][b][512][512] fp16
  // rec aliases inside ff1_16 (dead between FF uses)
  ushort* ts16   = ff1_16;             // [4096][512]
  ushort* sa16   = ff1_16 + 2097152;   // [2048][512]
  ushort* sn16   = ff1_16 + 3145728;   // [2048][512]
  ushort* sq16   = ff1_16 + 4194304;   // [2048][512]
  ushort* q2s16  = ff1_16 + 5242880;   // [2048][512]
  ushort* skv16  = ff1_16 + 6291456;   // [2048][128]

  // ---- mega weight prep (single launch; same per-tile math as 12 k_prep calls)
  PrepDescs pd;
  auto setd = [&](int i, const float* s, ushort* d, int K, int N, int nx, int ny, int nz, long zs){
    pd.src[i]=s; pd.dst[i]=d; pd.K[i]=K; pd.N[i]=N; pd.nx[i]=nx; pd.ny[i]=ny;
    pd.cnt[i]=nx*ny*nz; pd.zs[i]=zs;
  };
  setd(0,  Wq,          wqkh,           512,512,  16,16,6, 524288);
  setd(1,  Wk,          wqkh+262144,    512,512,  16,16,6, 524288);
  setd(2,  Wv,          wvT,            512,512,  16,16,6, 262144);
  setd(3,  Wo,          woT,            512,512,  16,16,6, 262144);
  setd(4,  ff_w1,       ffw1T,          512,2048, 64,16,6, 1048576);
  setd(5,  ff_w2,       ffw2T,          2048,512, 16,64,6, 1048576);
  setd(6,  Wo_state,    wostT,          512,512,  16,16,1, 262144);
  setd(7,  W_state_out, wstoutT,        512,512,  16,16,1, 262144);
  setd(8,  Wq2s,        wq2sh,          512,512,  16,16,1, 262144);
  setd(9,  Ws2q,        wsqkvh,         512,512,  16,16,1, 327680);
  setd(10, Ws2kv,       wsqkvh+262144,  512,128,  4,16,1,  327680);
  setd(11, W_logits,    wlogT,          512,20000,628,16,1,10289152);
  k_prep_all<<<29568,256,0,stream>>>(pd);

  for (int s=0;s<2;s++)
    k_vtrans<<<dim3(8,8,4),256,0,stream>>>(xl_mem_v + (size_t)s*1048576,
                                           xlvT + (size_t)s*1048576,
                                           262144L, 512, 1, 262144L, 32768L, 512);
  k_cvt<<<4096,256,0,stream>>>(xlk16, xl_mem_k, 1048576);

  k_embed<<<2048, 256, 0, stream>>>(x, tok_emb, hstate, 524288);
  k_postable<<<512, 128, 0, stream>>>(pw1,pb1,pw2,pb2,pw3,pb3, table);
  k_copy<<<4096, 256, 0, stream>>>(states_cur, states_in, 1048576);

  for (int l=0;l<6;l++){
    bool isxl = (l==4 || l==5);
    int xli = l-4;
    int src = (l==4)? 1 : 0;     // roll(-1)
    k_ln<<<4096,256,0,stream>>>(hstate, ln_g + l*512, xn16);
    float scale = 0.125f;
    const float* qsc = nullptr; const float* ksc = nullptr;
    if (l>=3){ qsc = q_scale + l*64; ksc = k_scale + l*64; scale = 8.f; }
    // q|k merged fp16 GEMM with fused rmsnorm (l>=3) + xl-k fp32 out (l=4,5)
    k_gemmqk<0><<<dim3(32,8),256,0,stream>>>(xn16,
        wqkh + (size_t)l*524288,
        q16, 512, 512, k16, 512, qsc, ksc,
        isxl ? out_xlk + (size_t)xli*1048576 : nullptr,
        0, 4096, 1024, 512);
    // v GEMM: fp16 V^T + (xl) fp32 out_xlv
    k_gemmh64<0,0,0,1><<<dim3(64,4),256,0,stream>>>(xn16, wvT + (size_t)l*262144,
        nullptr, nullptr, nullptr, vTb,
        isxl ? out_xlv + (size_t)xli*1048576 : nullptr, 4096,512,512);

    k_attn_win<<<dim3(16,8,4),256,0,stream>>>(
        q16, k16, vTb,
        isxl ? xlk16 + (size_t)src*1048576 : k16,
        isxl ? xlvT  + (size_t)src*1048576 : vTb,
        isxl ? 1 : 0, ao16, scale, table);

    k_gemmh64<1,0,0,0><<<dim3(64,4),256,0,stream>>>(ao16, woT + (size_t)l*262144,
        nullptr, hstate, nullptr, nullptr, nullptr, 4096,512,512);
    if (l==3){
      for (int nb=0;nb<2;nb++){
        k_ln<<<2048,256,0,stream>>>(states_cur, state_norm_g, sn16);
        k_gemmqk<0><<<dim3(16,5),256,0,stream>>>(sn16, wsqkvh,
            sq16, 512, 512, skv16, 128, nullptr, nullptr, nullptr, 0, 2048, 640, 512);
        k_vtrans16<<<dim3(8,1,4),256,0,stream>>>(skv16 + 64, svT, 65536L, 128, 32768L, 512);
        k_gemmqk<1><<<dim3(16,4),256,0,stream>>>(xn16, wq2sh,
            q2s16, 512, 512, nullptr, 0, nullptr, nullptr, nullptr, nb, 2048, 512, 512);
        k_attn_rec<<<dim3(16,8,4),256,0,stream>>>(
            q2s16, sq16, skv16, svT,
            k16 + (size_t)nb*262144, vTb + (size_t)nb*512,
            ts16 + (size_t)nb*262144, sa16);
        k_gemmh64<0,2,0,0><<<dim3(32,4),256,0,stream>>>(sa16, wstoutT, ema_beta,
            states_cur, nullptr, nullptr, nullptr, 2048,512,512);
      }
      k_gemmh64<1,0,0,0><<<dim3(64,4),256,0,stream>>>(ts16, wostT, nullptr,
          hstate, nullptr, nullptr, nullptr, 4096,512,512);
    }
    k_ln<<<4096,256,0,stream>>>(hstate, ff_g + l*512, xn16);
    k_gemmh<0,1,1><<<dim3(32,16),256,0,stream>>>(xn16, ffw1T + (size_t)l*1048576, ff_b1 + l*2048, nullptr, ff1_16, 4096,2048,512);
    k_gemmh64<1,0,0,0><<<dim3(64,4),256,0,stream>>>(ff1_16, ffw2T + (size_t)l*1048576, ff_b2 + l*512, hstate, nullptr, nullptr, nullptr, 4096,512,2048);
  }
  k_ln<<<4096,256,0,stream>>>(hstate, final_g, xn16);
  k_gemmh<0,0,0><<<dim3(32,157),256,0,stream>>>(xn16, wlogT, nullptr, out, nullptr, 4096,20000,512);
  k_copy<<<4096, 256, 0, stream>>>(out_states, states_cur, 1048576);
}

// Round 21
// 1448.225 us; speedup vs baseline: 1.0374x; 1.0176x over previous
//
#include <hip/hip_runtime.h>
#include <math.h>

// B=4 N=1024 V=20000 D=512 H=8 DH=64 W=512 NB=2 NS=512 FF=2048

typedef __attribute__((ext_vector_type(8))) _Float16 f16x8;
typedef __attribute__((ext_vector_type(4))) float f32x4;

__device__ __forceinline__ ushort f2h(float f){
  _Float16 h = (_Float16)f;
  return *reinterpret_cast<ushort*>(&h);
}
__device__ __forceinline__ uint pkh2(float a, float b){
  return (uint)f2h(a) | ((uint)f2h(b)<<16);
}

// ---------------- mega weight prep: 12 transposes in one launch ----------------
struct PrepDescs {
  const float* src[12];
  ushort*      dst[12];
  int K[12], N[12], nx[12], ny[12], cnt[12];
  long zs[12];
};

__global__ __launch_bounds__(256)
void k_prep_all(PrepDescs pd){
  __shared__ float tile[32][33];
  int bid = blockIdx.x, i = 0;
  while (i < 11 && bid >= pd.cnt[i]){ bid -= pd.cnt[i]; i++; }
  const int K = pd.K[i], N = pd.N[i], nx = pd.nx[i];
  const int z = bid/(nx*pd.ny[i]);
  const int rem = bid - z*nx*pd.ny[i];
  const int tyy = rem/nx, txx = rem - tyy*nx;
  const float* src = pd.src[i] + (size_t)z*K*N;
  ushort* dh = pd.dst[i] + (size_t)z*pd.zs[i];
  const int n0 = txx*32, k0 = tyy*32;
  const int tx = threadIdx.x&31, ty = threadIdx.x>>5;
#pragma unroll
  for (int u=0;u<4;u++){
    int kk = k0 + ty + u*8, nn = n0 + tx;
    tile[ty+u*8][tx] = (nn < N) ? src[(size_t)kk*N + nn] : 0.f;
  }
  __syncthreads();
#pragma unroll
  for (int u=0;u<4;u++){
    int nn = n0 + ty + u*8, kk = k0 + tx;
    dh[(size_t)nn*K + kk] = f2h(tile[tx][ty+u*8]);
  }
}

// ---------------- V transpose (startup xl mem only) ----------------
__global__ __launch_bounds__(256)
void k_vtrans(const float* __restrict__ src, ushort* __restrict__ dst,
              long sB, int sR, int sMH, long dB, long dH, int NK){
  __shared__ float tile[64][65];
  int kc = blockIdx.x, h = blockIdx.y, b = blockIdx.z;
  int t = threadIdx.x;
  int key = t>>2, doff = (t&3)*16;
  const float* sp = src + (size_t)b*sB + (size_t)(kc*64+key)*sR + (sMH? h*64:0) + doff;
#pragma unroll
  for (int u=0;u<4;u++){
    float4 v = *reinterpret_cast<const float4*>(sp + u*4);
    tile[key][doff+u*4+0]=v.x; tile[key][doff+u*4+1]=v.y;
    tile[key][doff+u*4+2]=v.z; tile[key][doff+u*4+3]=v.w;
  }
  __syncthreads();
  int d = t>>2, kf = (t&3)*16;
  ushort* dp = dst + (size_t)b*dB + (size_t)h*dH + (size_t)d*NK + kc*64 + kf;
  ushort tmp[16];
#pragma unroll
  for (int u=0;u<16;u++) tmp[u] = f2h(tile[kf+u][d]);
  uint4 o0 = make_uint4((uint)tmp[0]|((uint)tmp[1]<<16), (uint)tmp[2]|((uint)tmp[3]<<16),
                        (uint)tmp[4]|((uint)tmp[5]<<16), (uint)tmp[6]|((uint)tmp[7]<<16));
  uint4 o1 = make_uint4((uint)tmp[8]|((uint)tmp[9]<<16), (uint)tmp[10]|((uint)tmp[11]<<16),
                        (uint)tmp[12]|((uint)tmp[13]<<16),(uint)tmp[14]|((uint)tmp[15]<<16));
  *reinterpret_cast<uint4*>(dp)   = o0;
  *reinterpret_cast<uint4*>(dp+8) = o1;
}

// fp16 -> fp16 transpose (for skv16 V half)
__global__ __launch_bounds__(256)
void k_vtrans16(const ushort* __restrict__ src, ushort* __restrict__ dst,
                long sB, int sR, long dB, int NK){
  __shared__ ushort tile[64][72];
  int kc = blockIdx.x, b = blockIdx.z;
  int t = threadIdx.x;
  int key = t>>2, doff = (t&3)*16;
  const ushort* sp = src + (size_t)b*sB + (size_t)(kc*64+key)*sR + doff;
  *reinterpret_cast<uint4*>(&tile[key][doff])   = *reinterpret_cast<const uint4*>(sp);
  *reinterpret_cast<uint4*>(&tile[key][doff+8]) = *reinterpret_cast<const uint4*>(sp+8);
  __syncthreads();
  int d = t>>2, kf = (t&3)*16;
  ushort* dp = dst + (size_t)b*dB + (size_t)d*NK + kc*64 + kf;
  ushort tmp[16];
#pragma unroll
  for (int u=0;u<16;u++) tmp[u] = tile[kf+u][d];
  uint4 o0 = make_uint4((uint)tmp[0]|((uint)tmp[1]<<16), (uint)tmp[2]|((uint)tmp[3]<<16),
                        (uint)tmp[4]|((uint)tmp[5]<<16), (uint)tmp[6]|((uint)tmp[7]<<16));
  uint4 o1 = make_uint4((uint)tmp[8]|((uint)tmp[9]<<16), (uint)tmp[10]|((uint)tmp[11]<<16),
                        (uint)tmp[12]|((uint)tmp[13]<<16),(uint)tmp[14]|((uint)tmp[15]<<16));
  *reinterpret_cast<uint4*>(dp)   = o0;
  *reinterpret_cast<uint4*>(dp+8) = o1;
}

__global__ void k_cvt(ushort* __restrict__ dst, const float* __restrict__ src, int n2){
  int idx = blockIdx.x*blockDim.x + threadIdx.x;
  if (idx >= n2) return;
  reinterpret_cast<uint*>(dst)[idx] = pkh2(src[2*idx], src[2*idx+1]);
}

// ---------------- embed / postable ----------------
__global__ void k_embed(const int* __restrict__ x, const float* __restrict__ emb,
                        float* __restrict__ h, int total4){
  int idx = blockIdx.x*blockDim.x + threadIdx.x;
  if (idx >= total4) return;
  int row = idx >> 7;
  int c4  = idx & 127;
  int tok = x[row];
  reinterpret_cast<float4*>(h)[idx] =
      reinterpret_cast<const float4*>(emb)[(size_t)tok*128 + c4];
}

__global__ void k_postable(const float* __restrict__ w1, const float* __restrict__ b1,
                           const float* __restrict__ w2, const float* __restrict__ b2,
                           const float* __restrict__ w3, const float* __restrict__ b3,
                           float* __restrict__ table){
  __shared__ float h1[128];
  __shared__ float h2[128];
  int d = blockIdx.x, t = threadIdx.x;
  float a = (float)d * w1[t] + b1[t];
  h1[t] = a / (1.f + __expf(-a));
  __syncthreads();
  float acc = b2[t];
  for (int p=0;p<128;p++) acc += h1[p]*w2[p*128+t];
  h2[t] = acc / (1.f + __expf(-acc));
  __syncthreads();
  if (t < 8){
    float acc2 = b3[t];
    for (int p=0;p<128;p++) acc2 += h2[p]*w3[p*8+t];
    table[d*8+t] = acc2;
  }
}

// ---------------- layernorm -> fp16 (one wave per 512-col row, no barriers) --
__global__ void k_ln(const float* __restrict__ x, const float* __restrict__ g,
                     ushort* __restrict__ y16){
  int row = blockIdx.x*4 + (threadIdx.x>>6);
  int lane = threadIdx.x&63;
  const float* xr = x + (size_t)row*512 + lane*8;
  float4 a = *reinterpret_cast<const float4*>(xr);
  float4 b = *reinterpret_cast<const float4*>(xr+4);
  float s  = a.x+a.y+a.z+a.w + b.x+b.y+b.z+b.w;
  float ss = a.x*a.x+a.y*a.y+a.z*a.z+a.w*a.w
           + b.x*b.x+b.y*b.y+b.z*b.z+b.w*b.w;
#pragma unroll
  for (int o=1;o<64;o<<=1){ s += __shfl_xor(s,o); ss += __shfl_xor(ss,o); }
  float mu = s*(1.f/512.f);
  float var = ss*(1.f/512.f) - mu*mu;
  float rs = rsqrtf(var + 1e-5f);
  const float* gr = g + lane*8;
  float4 g0 = *reinterpret_cast<const float4*>(gr);
  float4 g1 = *reinterpret_cast<const float4*>(gr+4);
  uint4 o;
  o.x = pkh2((a.x-mu)*rs*g0.x, (a.y-mu)*rs*g0.y);
  o.y = pkh2((a.z-mu)*rs*g0.z, (a.w-mu)*rs*g0.w);
  o.z = pkh2((b.x-mu)*rs*g1.x, (b.y-mu)*rs*g1.y);
  o.w = pkh2((b.z-mu)*rs*g1.z, (b.w-mu)*rs*g1.w);
  *reinterpret_cast<uint4*>(y16 + (size_t)row*512 + lane*8) = o;
}

__device__ __forceinline__ float geluf(float x){
  float u = 1.5957691216f*(x + 0.044715f*x*x*x);
  return x / (1.f + __expf(-u));
}

// ---------------- fp16 MFMA GEMM 128x128 (FF1, logits) ----------------
template<int ACC, int EPI, int OUT16>
__global__ __launch_bounds__(256)
void k_gemmh(const ushort* __restrict__ A, const ushort* __restrict__ Bt,
             const float* __restrict__ bias, float* __restrict__ C,
             ushort* __restrict__ C16, int M, int N, int K){
  __shared__ ushort As[128][68];
  __shared__ ushort Bs[128][68];
  const int t = threadIdx.x;
  const int m0 = blockIdx.x*128, n0 = blockIdx.y*128;
  const int w = t>>6, lane = t&63;
  const int wm = (w>>1)*64, wn = (w&1)*64;
  const int fr = lane&15, fg = lane>>4;
  const int srow = t>>1, sko = (t&1)*32;

  f32x4 acc[4][4];
#pragma unroll
  for (int i=0;i<4;i++)
#pragma unroll
    for (int j=0;j<4;j++){ acc[i][j][0]=0.f; acc[i][j][1]=0.f; acc[i][j][2]=0.f; acc[i][j][3]=0.f; }

  const ushort* ap = A  + (size_t)(m0+srow)*K + sko;
  const ushort* bp = Bt + (size_t)(n0+srow)*K + sko;

  for (int k0=0; k0<K; k0+=64){
    uint4 av[4], bv[4];
#pragma unroll
    for (int u=0;u<4;u++){
      av[u] = *reinterpret_cast<const uint4*>(ap + k0 + u*8);
      bv[u] = *reinterpret_cast<const uint4*>(bp + k0 + u*8);
    }
#pragma unroll
    for (int u=0;u<4;u++){
      *reinterpret_cast<uint4*>(&As[srow][sko+u*8]) = av[u];
      *reinterpret_cast<uint4*>(&Bs[srow][sko+u*8]) = bv[u];
    }
    __syncthreads();
#pragma unroll
    for (int kk=0;kk<2;kk++){
      f16x8 af[4], bf[4];
#pragma unroll
      for (int mi=0;mi<4;mi++)
        af[mi] = *reinterpret_cast<const f16x8*>(&As[wm+mi*16+fr][kk*32+fg*8]);
#pragma unroll
      for (int nj=0;nj<4;nj++)
        bf[nj] = *reinterpret_cast<const f16x8*>(&Bs[wn+nj*16+fr][kk*32+fg*8]);
#pragma unroll
      for (int mi=0;mi<4;mi++)
#pragma unroll
        for (int nj=0;nj<4;nj++)
          acc[mi][nj] = __builtin_amdgcn_mfma_f32_16x16x32_f16(af[mi], bf[nj], acc[mi][nj], 0,0,0);
    }
    __syncthreads();
  }
#pragma unroll
  for (int mi=0;mi<4;mi++){
#pragma unroll
    for (int r=0;r<4;r++){
      int row = m0 + wm + mi*16 + fg*4 + r;
#pragma unroll
      for (int nj=0;nj<4;nj++){
        int col = n0 + wn + nj*16 + fr;
        if (col < N){
          float val = acc[mi][nj][r];
          if (bias) val += bias[col];
          if (EPI==1) val = geluf(val);
          if (OUT16){
            C16[(size_t)row*N + col] = f2h(val);
          } else {
            if (ACC) C[(size_t)row*N + col] += val; else C[(size_t)row*N + col] = val;
          }
        }
      }
    }
  }
}

// ---------------- fp16 MFMA GEMM 128x128 with split out + rms + remap --------
template<int REMAP>
__global__ __launch_bounds__(256)
void k_gemmqk(const ushort* __restrict__ A, const ushort* __restrict__ Bt,
              ushort* __restrict__ C1h, int ld1, int N1,
              ushort* __restrict__ C2h, int ld2,
              const float* __restrict__ qsc, const float* __restrict__ ksc,
              float* __restrict__ xlk,
              int nb, int M, int N, int K){
  __shared__ ushort As[128][68];
  __shared__ ushort Bs[128][68];
  const int t = threadIdx.x;
  const int m0 = blockIdx.x*128, n0 = blockIdx.y*128;
  const int w = t>>6, lane = t&63;
  const int wm = (w>>1)*64, wn = (w&1)*64;
  const int fr = lane&15, fg = lane>>4;
  const int srow = t>>1, sko = (t&1)*32;

  f32x4 acc[4][4];
#pragma unroll
  for (int i=0;i<4;i++)
#pragma unroll
    for (int j=0;j<4;j++){ acc[i][j][0]=0.f; acc[i][j][1]=0.f; acc[i][j][2]=0.f; acc[i][j][3]=0.f; }

  int mrow = m0 + srow;
  int arow = REMAP ? ((mrow>>9)*1024 + nb*512 + (mrow&511)) : mrow;
  const ushort* ap = A  + (size_t)arow*K + sko;
  const ushort* bp = Bt + (size_t)(n0+srow)*K + sko;

  for (int k0=0; k0<K; k0+=64){
    uint4 av[4], bv[4];
#pragma unroll
    for (int u=0;u<4;u++){
      av[u] = *reinterpret_cast<const uint4*>(ap + k0 + u*8);
      bv[u] = *reinterpret_cast<const uint4*>(bp + k0 + u*8);
    }
#pragma unroll
    for (int u=0;u<4;u++){
      *reinterpret_cast<uint4*>(&As[srow][sko+u*8]) = av[u];
      *reinterpret_cast<uint4*>(&Bs[srow][sko+u*8]) = bv[u];
    }
    __syncthreads();
#pragma unroll
    for (int kk=0;kk<2;kk++){
      f16x8 af[4], bf[4];
#pragma unroll
      for (int mi=0;mi<4;mi++)
        af[mi] = *reinterpret_cast<const f16x8*>(&As[wm+mi*16+fr][kk*32+fg*8]);
#pragma unroll
      for (int nj=0;nj<4;nj++)
        bf[nj] = *reinterpret_cast<const f16x8*>(&Bs[wn+nj*16+fr][kk*32+fg*8]);
#pragma unroll
      for (int mi=0;mi<4;mi++)
#pragma unroll
        for (int nj=0;nj<4;nj++)
          acc[mi][nj] = __builtin_amdgcn_mfma_f32_16x16x32_f16(af[mi], bf[nj], acc[mi][nj], 0,0,0);
    }
    __syncthreads();
  }
#pragma unroll
  for (int mi=0;mi<4;mi++){
#pragma unroll
    for (int r=0;r<4;r++){
      int row = m0 + wm + mi*16 + fg*4 + r;
      float vals[4];
#pragma unroll
      for (int nj=0;nj<4;nj++) vals[nj] = acc[mi][nj][r];
      if (qsc){
        float ss = vals[0]*vals[0]+vals[1]*vals[1]+vals[2]*vals[2]+vals[3]*vals[3];
        ss += __shfl_xor(ss,1);
        ss += __shfl_xor(ss,2);
        ss += __shfl_xor(ss,4);
        ss += __shfl_xor(ss,8);
        float rs = rsqrtf(ss + 1e-12f);
        const float* sc = ((n0+wn) < N1) ? qsc : ksc;
#pragma unroll
        for (int nj=0;nj<4;nj++) vals[nj] = vals[nj]*rs*sc[nj*16+fr];
      }
#pragma unroll
      for (int nj=0;nj<4;nj++){
        int col = n0 + wn + nj*16 + fr;
        float val = vals[nj];
        if (col < N1){
          C1h[(size_t)row*ld1 + col] = f2h(val);
        } else if (col < N){
          if (C2h) C2h[(size_t)row*ld2 + (col-N1)] = f2h(val);
          if (xlk && (row&1023) >= 512)
            xlk[((size_t)(row>>10)*512 + (row&1023) - 512)*512 + (col-N1)] = val;
        }
      }
    }
  }
}

// ---------------- fp16 MFMA GEMM 64x128 (N=512 class) ------------------------
// EPI: 0 none, 1 gelu, 2 ema. VT=1: fp16 transposed vT + optional fp32 xlv.
template<int ACC, int EPI, int OUT16, int VT>
__global__ __launch_bounds__(256)
void k_gemmh64(const ushort* __restrict__ A, const ushort* __restrict__ Bt,
               const float* __restrict__ bias, float* __restrict__ C,
               ushort* __restrict__ C16, ushort* __restrict__ vT,
               float* __restrict__ xlv, int M, int N, int K){
  __shared__ ushort As[64][68];
  __shared__ ushort Bs[128][68];
  const int t = threadIdx.x;
  const int m0 = blockIdx.x*64, n0 = blockIdx.y*128;
  const int w = t>>6, lane = t&63;
  const int wm = (w>>1)*32, wn = (w&1)*64;
  const int fr = lane&15, fg = lane>>4;
  const int srowA = t>>2, skoA = (t&3)*16;
  const int srowB = t>>1, skoB = (t&1)*32;

  f32x4 acc[2][4];
#pragma unroll
  for (int i=0;i<2;i++)
#pragma unroll
    for (int j=0;j<4;j++){ acc[i][j][0]=0.f; acc[i][j][1]=0.f; acc[i][j][2]=0.f; acc[i][j][3]=0.f; }

  const ushort* ap = A  + (size_t)(m0+srowA)*K + skoA;
  const ushort* bp = Bt + (size_t)(n0+srowB)*K + skoB;

  for (int k0=0; k0<K; k0+=64){
    uint4 a0 = *reinterpret_cast<const uint4*>(ap + k0);
    uint4 a1 = *reinterpret_cast<const uint4*>(ap + k0 + 8);
    uint4 b0 = *reinterpret_cast<const uint4*>(bp + k0);
    uint4 b1 = *reinterpret_cast<const uint4*>(bp + k0 + 8);
    uint4 b2 = *reinterpret_cast<const uint4*>(bp + k0 + 16);
    uint4 b3 = *reinterpret_cast<const uint4*>(bp + k0 + 24);
    *reinterpret_cast<uint4*>(&As[srowA][skoA])    = a0;
    *reinterpret_cast<uint4*>(&As[srowA][skoA+8])  = a1;
    *reinterpret_cast<uint4*>(&Bs[srowB][skoB])    = b0;
    *reinterpret_cast<uint4*>(&Bs[srowB][skoB+8])  = b1;
    *reinterpret_cast<uint4*>(&Bs[srowB][skoB+16]) = b2;
    *reinterpret_cast<uint4*>(&Bs[srowB][skoB+24]) = b3;
    __syncthreads();
#pragma unroll
    for (int kk=0;kk<2;kk++){
      f16x8 af[2], bf[4];
#pragma unroll
      for (int mi=0;mi<2;mi++)
        af[mi] = *reinterpret_cast<const f16x8*>(&As[wm+mi*16+fr][kk*32+fg*8]);
#pragma unroll
      for (int nj=0;nj<4;nj++)
        bf[nj] = *reinterpret_cast<const f16x8*>(&Bs[wn+nj*16+fr][kk*32+fg*8]);
#pragma unroll
      for (int mi=0;mi<2;mi++)
#pragma unroll
        for (int nj=0;nj<4;nj++)
          acc[mi][nj] = __builtin_amdgcn_mfma_f32_16x16x32_f16(af[mi], bf[nj], acc[mi][nj], 0,0,0);
    }
    __syncthreads();
  }
#pragma unroll
  for (int mi=0;mi<2;mi++){
#pragma unroll
    for (int r=0;r<4;r++){
      int row = m0 + wm + mi*16 + fg*4 + r;
#pragma unroll
      for (int nj=0;nj<4;nj++){
        int col = n0 + wn + nj*16 + fr;
        if (col < N){
          float val = acc[mi][nj][r];
          if (EPI==2){
            size_t idx = (size_t)row*N + col;
            float old = C[idx];
            float dec = 1.f/(1.f+__expf(-bias[col]));
            C[idx] = dec*old + (1.f-dec)*val;
          } else {
            if (bias) val += bias[col];
            if (EPI==1) val = geluf(val);
            if (OUT16){
              if (C16) C16[(size_t)row*N + col] = f2h(val);
            } else if (C){
              if (ACC) C[(size_t)row*N + col] += val; else C[(size_t)row*N + col] = val;
            }
            if (VT && xlv && (row&1023) >= 512)
              xlv[((size_t)(row>>10)*512 + (row&1023) - 512)*512 + col] = val;
          }
        }
      }
    }
  }
  if (VT){
#pragma unroll
    for (int mi=0;mi<2;mi++)
#pragma unroll
      for (int r=0;r<4;r++)
#pragma unroll
        for (int nj=0;nj<4;nj++)
          Bs[wn+nj*16+fr][wm+mi*16+fg*4+r] = f2h(acc[mi][nj][r]);
    __syncthreads();
    int c = t>>1, half = t&1;
    int hh = (n0+c)>>6, dd = (n0+c)&63;
    int bb = m0>>10, posb = m0&1023;
    ushort* dp = vT + (size_t)bb*524288 + (size_t)hh*65536 + (size_t)dd*1024 + posb + half*32;
#pragma unroll
    for (int u=0;u<4;u++)
      *reinterpret_cast<uint4*>(dp + u*8) = *reinterpret_cast<const uint4*>(&Bs[c][half*32 + u*8]);
  }
}

// ---------------- merged windowed MFMA flash attention -----------------------
__global__ __launch_bounds__(256)
void k_attn_win(const ushort* __restrict__ q16, const ushort* __restrict__ k16,
                const ushort* __restrict__ vTb,
                const ushort* __restrict__ xlK, const ushort* __restrict__ xlVT,
                int isxl, ushort* __restrict__ O, float scale,
                const float* __restrict__ table){
  __shared__ ushort Qs[64][72];
  __shared__ ushort Ks[64][72];
  __shared__ ushort Vs[64][72];
  __shared__ ushort Pw[4][16][72];
  __shared__ float tcol[512];
  const int b = blockIdx.z, h = blockIdx.y;
  const int nb = blockIdx.x>>3, qt = blockIdx.x&7;
  const int t = threadIdx.x, w = t>>6, lane = t&63;
  const int fr = lane&15, fg = lane>>4;
  tcol[t]     = table[t*8 + h];
  tcol[t+256] = table[(t+256)*8 + h];

  const ushort* Q  = q16 + (size_t)nb*262144;
  const ushort* K1 = k16 + (size_t)nb*262144;
  const ushort* V1 = vTb + (size_t)nb*512;
  ushort* Op = O + (size_t)nb*262144;
  const int has_mem = (nb==1) || isxl;
  const ushort* K0; long k0B; const ushort* V0; long vt0B, vt0H; int vt0D;
  if (nb==1){ K0=k16; k0B=524288; V0=vTb; vt0B=524288; vt0H=65536; vt0D=1024; }
  else if (isxl){ K0=xlK; k0B=262144; V0=xlVT; vt0B=262144; vt0H=32768; vt0D=512; }
  else { K0=k16; k0B=524288; V0=vTb; vt0B=524288; vt0H=65536; vt0D=1024; }

  {
    int qrow = t>>2, doff = (t&3)*16;
    const ushort* qp = Q + (size_t)b*524288 + (size_t)(qt*64+qrow)*512 + h*64 + doff;
    *reinterpret_cast<uint4*>(&Qs[qrow][doff])   = *reinterpret_cast<const uint4*>(qp);
    *reinterpret_cast<uint4*>(&Qs[qrow][doff+8]) = *reinterpret_cast<const uint4*>(qp+8);
  }
  __syncthreads();
  f16x8 aq[2];
  aq[0] = *reinterpret_cast<const f16x8*>(&Qs[w*16+fr][fg*8]);
  aq[1] = *reinterpret_cast<const f16x8*>(&Qs[w*16+fr][32+fg*8]);

  f32x4 so[4];
#pragma unroll
  for (int dt=0;dt<4;dt++){ so[dt][0]=0.f; so[dt][1]=0.f; so[dt][2]=0.f; so[dt][3]=0.f; }
  float m[4] = {-1e30f,-1e30f,-1e30f,-1e30f};
  float lsum[4] = {0.f,0.f,0.f,0.f};

  const int srow = t>>2, sdo = (t&3)*16;
  const int vd = t>>2,   vkf = (t&3)*16;

  int jt0 = has_mem ? qt : 8;
  int jt1 = qt + 8; if (jt1 > 15) jt1 = 15;

  for (int jt=jt0; jt<=jt1; jt++){
    {
      int key = jt*64 + srow;
      const ushort* kp;
      if (key < 512) kp = K0 + (size_t)b*k0B + (size_t)key*512 + h*64 + sdo;
      else           kp = K1 + (size_t)b*524288 + (size_t)(key-512)*512 + h*64 + sdo;
      *reinterpret_cast<uint4*>(&Ks[srow][sdo])   = *reinterpret_cast<const uint4*>(kp);
      *reinterpret_cast<uint4*>(&Ks[srow][sdo+8]) = *reinterpret_cast<const uint4*>(kp+8);
    }
    {
      const ushort* vp;
      if (jt*64 < 512) vp = V0 + (size_t)b*vt0B + (size_t)h*vt0H + (size_t)vd*vt0D + jt*64 + vkf;
      else             vp = V1 + (size_t)b*524288 + (size_t)h*65536 + (size_t)vd*1024 + (jt*64-512) + vkf;
      *reinterpret_cast<uint4*>(&Vs[vd][vkf])   = *reinterpret_cast<const uint4*>(vp);
      *reinterpret_cast<uint4*>(&Vs[vd][vkf+8]) = *reinterpret_cast<const uint4*>(vp+8);
    }
    __syncthreads();
    f32x4 sacc[4];
#pragma unroll
    for (int kt=0;kt<4;kt++){ sacc[kt][0]=0.f; sacc[kt][1]=0.f; sacc[kt][2]=0.f; sacc[kt][3]=0.f; }
#pragma unroll
    for (int ks=0;ks<2;ks++){
#pragma unroll
      for (int kt=0;kt<4;kt++){
        f16x8 bf = *reinterpret_cast<const f16x8*>(&Ks[kt*16+fr][ks*32+fg*8]);
        sacc[kt] = __builtin_amdgcn_mfma_f32_16x16x32_f16(aq[ks], bf, sacc[kt], 0,0,0);
      }
    }
#pragma unroll
    for (int r=0;r<4;r++){
      float sv[4];
      int ia = qt*64 + w*16 + fg*4 + r;
#pragma unroll
      for (int kt=0;kt<4;kt++){
        float s = sacc[kt][r]*scale;
        int jg = jt*64 + kt*16 + fr;
        bool valid = (jg > ia) && (jg <= ia+512) && (has_mem || jg >= 512);
        sv[kt] = valid ? s + tcol[ia+512-jg] : -1e9f;
      }
      float tm = fmaxf(fmaxf(sv[0],sv[1]), fmaxf(sv[2],sv[3]));
      tm = fmaxf(tm, __shfl_xor(tm,1));
      tm = fmaxf(tm, __shfl_xor(tm,2));
      tm = fmaxf(tm, __shfl_xor(tm,4));
      tm = fmaxf(tm, __shfl_xor(tm,8));
      float mn = fmaxf(m[r], tm);
      float c = __expf(m[r]-mn);
      m[r] = mn;
      float ps = 0.f;
#pragma unroll
      for (int kt=0;kt<4;kt++){
        float pp = (sv[kt] <= -1e8f) ? 0.f : __expf(sv[kt]-mn);
        ps += pp;
        Pw[w][fg*4+r][kt*16+fr] = f2h(pp);
      }
      ps += __shfl_xor(ps,1);
      ps += __shfl_xor(ps,2);
      ps += __shfl_xor(ps,4);
      ps += __shfl_xor(ps,8);
      lsum[r] = lsum[r]*c + ps;
#pragma unroll
      for (int dt=0;dt<4;dt++) so[dt][r] *= c;
    }
#pragma unroll
    for (int ks=0;ks<2;ks++){
      f16x8 pa = *reinterpret_cast<const f16x8*>(&Pw[w][fr][ks*32+fg*8]);
#pragma unroll
      for (int dt=0;dt<4;dt++){
        f16x8 bv = *reinterpret_cast<const f16x8*>(&Vs[dt*16+fr][ks*32+fg*8]);
        so[dt] = __builtin_amdgcn_mfma_f32_16x16x32_f16(pa, bv, so[dt], 0,0,0);
      }
    }
    __syncthreads();
  }
#pragma unroll
  for (int r=0;r<4;r++){
    int row = qt*64 + w*16 + fg*4 + r;
    float inv = 1.f / lsum[r];
    ushort* op = Op + (size_t)b*524288 + (size_t)row*512 + h*64;
#pragma unroll
    for (int dt=0;dt<4;dt++)
      op[dt*16+fr] = f2h(so[dt][r]*inv);
  }
}

// ---------------- merged rec-layer attentions ----------------
__global__ __launch_bounds__(256)
void k_attn_rec(const ushort* __restrict__ q2s, const ushort* __restrict__ sq,
                const ushort* __restrict__ skv, const ushort* __restrict__ svT,
                const ushort* __restrict__ kblk, const ushort* __restrict__ vblk,
                ushort* __restrict__ ts, ushort* __restrict__ sa){
  __shared__ ushort Qs[64][72];
  __shared__ ushort Ks[64][72];
  __shared__ ushort Vs[64][72];
  __shared__ ushort Pw[4][16][72];
  const int b = blockIdx.z, h = blockIdx.y;
  const int task = blockIdx.x>>3, qt = blockIdx.x&7;
  const int t = threadIdx.x, w = t>>6, lane = t&63;
  const int fr = lane&15, fg = lane>>4;

  const ushort* Q; const ushort* K1; int k1R, k1H;
  const ushort* VT1; long vt1B, vt1H; int vt1D;
  int nt; ushort* O; long oB;
  if (task==0){
    Q=q2s; K1=skv; k1R=128; k1H=0;
    VT1=svT; vt1B=32768; vt1H=0; vt1D=512;
    nt=8; O=ts; oB=524288;
  } else {
    Q=sq; K1=kblk; k1R=512; k1H=1;
    VT1=vblk; vt1B=524288; vt1H=65536; vt1D=1024;
    nt=16; O=sa; oB=262144;
  }

  {
    int qrow = t>>2, doff = (t&3)*16;
    const ushort* qp = Q + (size_t)b*262144 + (size_t)(qt*64+qrow)*512 + h*64 + doff;
    *reinterpret_cast<uint4*>(&Qs[qrow][doff])   = *reinterpret_cast<const uint4*>(qp);
    *reinterpret_cast<uint4*>(&Qs[qrow][doff+8]) = *reinterpret_cast<const uint4*>(qp+8);
  }
  __syncthreads();
  f16x8 aq[2];
  aq[0] = *reinterpret_cast<const f16x8*>(&Qs[w*16+fr][fg*8]);
  aq[1] = *reinterpret_cast<const f16x8*>(&Qs[w*16+fr][32+fg*8]);

  f32x4 so[4];
#pragma unroll
  for (int dt=0;dt<4;dt++){ so[dt][0]=0.f; so[dt][1]=0.f; so[dt][2]=0.f; so[dt][3]=0.f; }
  float m[4] = {-1e30f,-1e30f,-1e30f,-1e30f};
  float lsum[4] = {0.f,0.f,0.f,0.f};

  const int srow = t>>2, sdo = (t&3)*16;
  const int vd = t>>2,   vkf = (t&3)*16;

  for (int jt=0; jt<nt; jt++){
    {
      int key = jt*64 + srow;
      const ushort* kp;
      if (key < 512) kp = skv + (size_t)b*65536 + (size_t)key*128 + sdo;
      else           kp = K1 + (size_t)b*524288 + (size_t)(key-512)*k1R + (k1H? h*64:0) + sdo;
      *reinterpret_cast<uint4*>(&Ks[srow][sdo])   = *reinterpret_cast<const uint4*>(kp);
      *reinterpret_cast<uint4*>(&Ks[srow][sdo+8]) = *reinterpret_cast<const uint4*>(kp+8);
    }
    {
      const ushort* vp;
      if (jt*64 < 512) vp = svT + (size_t)b*32768 + (size_t)vd*512 + jt*64 + vkf;
      else             vp = VT1 + (size_t)b*vt1B + (size_t)h*vt1H + (size_t)vd*vt1D + (jt*64-512) + vkf;
      *reinterpret_cast<uint4*>(&Vs[vd][vkf])   = *reinterpret_cast<const uint4*>(vp);
      *reinterpret_cast<uint4*>(&Vs[vd][vkf+8]) = *reinterpret_cast<const uint4*>(vp+8);
    }
    __syncthreads();
    f32x4 sacc[4];
#pragma unroll
    for (int kt=0;kt<4;kt++){ sacc[kt][0]=0.f; sacc[kt][1]=0.f; sacc[kt][2]=0.f; sacc[kt][3]=0.f; }
#pragma unroll
    for (int ks=0;ks<2;ks++){
#pragma unroll
      for (int kt=0;kt<4;kt++){
        f16x8 bf = *reinterpret_cast<const f16x8*>(&Ks[kt*16+fr][ks*32+fg*8]);
        sacc[kt] = __builtin_amdgcn_mfma_f32_16x16x32_f16(aq[ks], bf, sacc[kt], 0,0,0);
      }
    }
#pragma unroll
    for (int r=0;r<4;r++){
      float sv[4];
#pragma unroll
      for (int kt=0;kt<4;kt++) sv[kt] = sacc[kt][r]*0.125f;
      float tm = fmaxf(fmaxf(sv[0],sv[1]), fmaxf(sv[2],sv[3]));
      tm = fmaxf(tm, __shfl_xor(tm,1));
      tm = fmaxf(tm, __shfl_xor(tm,2));
      tm = fmaxf(tm, __shfl_xor(tm,4));
      tm = fmaxf(tm, __shfl_xor(tm,8));
      float mn = fmaxf(m[r], tm);
      float c = __expf(m[r]-mn);
      m[r] = mn;
      float ps = 0.f;
#pragma unroll
      for (int kt=0;kt<4;kt++){
        float pp = __expf(sv[kt]-mn);
        ps += pp;
        Pw[w][fg*4+r][kt*16+fr] = f2h(pp);
      }
      ps += __shfl_xor(ps,1);
      ps += __shfl_xor(ps,2);
      ps += __shfl_xor(ps,4);
      ps += __shfl_xor(ps,8);
      lsum[r] = lsum[r]*c + ps;
#pragma unroll
      for (int dt=0;dt<4;dt++) so[dt][r] *= c;
    }
#pragma unroll
    for (int ks=0;ks<2;ks++){
      f16x8 pa = *reinterpret_cast<const f16x8*>(&Pw[w][fr][ks*32+fg*8]);
#pragma unroll
      for (int dt=0;dt<4;dt++){
        f16x8 bv = *reinterpret_cast<const f16x8*>(&Vs[dt*16+fr][ks*32+fg*8]);
        so[dt] = __builtin_amdgcn_mfma_f32_16x16x32_f16(pa, bv, so[dt], 0,0,0);
      }
    }
    __syncthreads();
  }
#pragma unroll
  for (int r=0;r<4;r++){
    int row = qt*64 + w*16 + fg*4 + r;
    float inv = 1.f / lsum[r];
    ushort* op = O + (size_t)b*oB + (size_t)row*512 + h*64;
#pragma unroll
    for (int dt=0;dt<4;dt++)
      op[dt*16+fr] = f2h(so[dt][r]*inv);
  }
}

// ---------------- small utility kernels ----------------
__global__ void k_copy(float* __restrict__ dst, const float* __restrict__ src, int n){
  int idx = blockIdx.x*blockDim.x + threadIdx.x;
  if (idx < n) dst[idx] = src[idx];
}

// ---------------- launcher ----------------
extern "C" void kernel_launch(void* const* d_in, const int* in_sizes, int n_in,
                              void* d_out, int out_size, void* d_ws, size_t ws_size,
                              hipStream_t stream){
  // floats 12,599,296 B + ushorts 106,954,752 B = 119,554,048 B
  if (ws_size < (size_t)119554048) return;

  const int*   x        = (const int*)  d_in[0];
  const float* tok_emb  = (const float*)d_in[1];
  const float* pw1 = (const float*)d_in[2];
  const float* pb1 = (const float*)d_in[3];
  const float* pw2 = (const float*)d_in[4];
  const float* pb2 = (const float*)d_in[5];
  const float* pw3 = (const float*)d_in[6];
  const float* pb3 = (const float*)d_in[7];
  const float* ln_g = (const float*)d_in[8];
  const float* Wq = (const float*)d_in[9];
  const float* Wk = (const float*)d_in[10];
  const float* Wv = (const float*)d_in[11];
  const float* Wo = (const float*)d_in[12];
  const float* q_scale = (const float*)d_in[13];
  const float* k_scale = (const float*)d_in[14];
  const float* Wo_state = (const float*)d_in[15];
  const float* state_norm_g = (const float*)d_in[16];
  const float* Wq2s = (const float*)d_in[17];
  const float* Ws2q = (const float*)d_in[18];
  const float* Ws2kv = (const float*)d_in[19];
  const float* W_state_out = (const float*)d_in[20];
  const float* ema_beta = (const float*)d_in[21];
  const float* ff_g = (const float*)d_in[22];
  const float* ff_w1 = (const float*)d_in[23];
  const float* ff_b1 = (const float*)d_in[24];
  const float* ff_w2 = (const float*)d_in[25];
  const float* ff_b2 = (const float*)d_in[26];
  const float* final_g = (const float*)d_in[27];
  const float* W_logits = (const float*)d_in[28];
  const float* xl_mem_k = (const float*)d_in[29];
  const float* xl_mem_v = (const float*)d_in[30];
  const float* states_in = (const float*)d_in[31];

  float* out = (float*)d_out;
  float* out_xlk    = out + 81920000;
  float* out_xlv    = out + 84017152;
  float* out_states = out + 86114304;

  float* p = (float*)d_ws;
  float* hstate   = p; p += 2097152;
  float* states_cur = p; p += 1048576;
  float* table    = p; p += 4096;

  ushort* us = (ushort*)p;
  ushort* wqkh  = us; us += 3145728;   // [6][1024][512]: rows 0-511 q, 512-1023 k
  ushort* wvT   = us; us += 1572864;
  ushort* woT   = us; us += 1572864;
  ushort* ffw1T = us; us += 6291456;
  ushort* ffw2T = us; us += 6291456;
  ushort* wostT = us; us += 262144;
  ushort* wstoutT = us; us += 262144;
  ushort* wq2sh = us; us += 262144;
  ushort* wsqkvh = us; us += 327680;   // [640][512]: rows 0-511 Ws2q, 512-639 Ws2kv
  ushort* wlogT  = us; us += 10289152; // [20096][512]
  ushort* vTb   = us; us += 2097152;   // [b][h][64][1024]
  ushort* xlvT  = us; us += 2097152;   // [2][b][h][64][512]
  ushort* svT   = us; us += 131072;    // [b][64][512]
  ushort* xn16  = us; us += 2097152;
  ushort* ao16  = us; us += 2097152;
  ushort* ff1_16 = us; us += 8388608;  // [4096][2048] + rec aliases
  ushort* q16   = us; us += 2097152;
  ushort* k16   = us; us += 2097152;
  ushort* xlk16 = us; us += 2097152;   // [2][b][512][512] fp16
  // rec aliases inside ff1_16 (dead between FF uses)
  ushort* ts16   = ff1_16;             // [4096][512]
  ushort* sa16   = ff1_16 + 2097152;   // [2048][512]
  ushort* sn16   = ff1_16 + 3145728;   // [2048][512]
  ushort* sq16   = ff1_16 + 4194304;   // [2048][512]
  ushort* q2s16  = ff1_16 + 5242880;   // [2048][512]
  ushort* skv16  = ff1_16 + 6291456;   // [2048][128]

  // ---- mega weight prep (single launch; same per-tile math as 12 k_prep calls)
  PrepDescs pd;
  auto setd = [&](int i, const float* s, ushort* d, int K, int N, int nx, int ny, int nz, long zs){
    pd.src[i]=s; pd.dst[i]=d; pd.K[i]=K; pd.N[i]=N; pd.nx[i]=nx; pd.ny[i]=ny;
    pd.cnt[i]=nx*ny*nz; pd.zs[i]=zs;
  };
  setd(0,  Wq,          wqkh,           512,512,  16,16,6, 524288);
  setd(1,  Wk,          wqkh+262144,    512,512,  16,16,6, 524288);
  setd(2,  Wv,          wvT,            512,512,  16,16,6, 262144);
  setd(3,  Wo,          woT,            512,512,  16,16,6, 262144);
  setd(4,  ff_w1,       ffw1T,          512,2048, 64,16,6, 1048576);
  setd(5,  ff_w2,       ffw2T,          2048,512, 16,64,6, 1048576);
  setd(6,  Wo_state,    wostT,          512,512,  16,16,1, 262144);
  setd(7,  W_state_out, wstoutT,        512,512,  16,16,1, 262144);
  setd(8,  Wq2s,        wq2sh,          512,512,  16,16,1, 262144);
  setd(9,  Ws2q,        wsqkvh,         512,512,  16,16,1, 327680);
  setd(10, Ws2kv,       wsqkvh+262144,  512,128,  4,16,1,  327680);
  setd(11, W_logits,    wlogT,          512,20000,628,16,1,10289152);
  k_prep_all<<<29568,256,0,stream>>>(pd);

  for (int s=0;s<2;s++)
    k_vtrans<<<dim3(8,8,4),256,0,stream>>>(xl_mem_v + (size_t)s*1048576,
                                           xlvT + (size_t)s*1048576,
                                           262144L, 512, 1, 262144L, 32768L, 512);
  k_cvt<<<4096,256,0,stream>>>(xlk16, xl_mem_k, 1048576);

  k_embed<<<2048, 256, 0, stream>>>(x, tok_emb, hstate, 524288);
  k_postable<<<512, 128, 0, stream>>>(pw1,pb1,pw2,pb2,pw3,pb3, table);
  k_copy<<<4096, 256, 0, stream>>>(states_cur, states_in, 1048576);

  for (int l=0;l<6;l++){
    bool isxl = (l==4 || l==5);
    int xli = l-4;
    int src = (l==4)? 1 : 0;     // roll(-1)
    k_ln<<<1024,256,0,stream>>>(hstate, ln_g + l*512, xn16);
    float scale = 0.125f;
    const float* qsc = nullptr; const float* ksc = nullptr;
    if (l>=3){ qsc = q_scale + l*64; ksc = k_scale + l*64; scale = 8.f; }
    // q|k merged fp16 GEMM with fused rmsnorm (l>=3) + xl-k fp32 out (l=4,5)
    k_gemmqk<0><<<dim3(32,8),256,0,stream>>>(xn16,
        wqkh + (size_t)l*524288,
        q16, 512, 512, k16, 512, qsc, ksc,
        isxl ? out_xlk + (size_t)xli*1048576 : nullptr,
        0, 4096, 1024, 512);
    // v GEMM: fp16 V^T + (xl) fp32 out_xlv
    k_gemmh64<0,0,0,1><<<dim3(64,4),256,0,stream>>>(xn16, wvT + (size_t)l*262144,
        nullptr, nullptr, nullptr, vTb,
        isxl ? out_xlv + (size_t)xli*1048576 : nullptr, 4096,512,512);

    k_attn_win<<<dim3(16,8,4),256,0,stream>>>(
        q16, k16, vTb,
        isxl ? xlk16 + (size_t)src*1048576 : k16,
        isxl ? xlvT  + (size_t)src*1048576 : vTb,
        isxl ? 1 : 0, ao16, scale, table);

    k_gemmh64<1,0,0,0><<<dim3(64,4),256,0,stream>>>(ao16, woT + (size_t)l*262144,
        nullptr, hstate, nullptr, nullptr, nullptr, 4096,512,512);
    if (l==3){
      for (int nb=0;nb<2;nb++){
        k_ln<<<512,256,0,stream>>>(states_cur, state_norm_g, sn16);
        k_gemmqk<0><<<dim3(16,5),256,0,stream>>>(sn16, wsqkvh,
            sq16, 512, 512, skv16, 128, nullptr, nullptr, nullptr, 0, 2048, 640, 512);
        k_vtrans16<<<dim3(8,1,4),256,0,stream>>>(skv16 + 64, svT, 65536L, 128, 32768L, 512);
        k_gemmqk<1><<<dim3(16,4),256,0,stream>>>(xn16, wq2sh,
            q2s16, 512, 512, nullptr, 0, nullptr, nullptr, nullptr, nb, 2048, 512, 512);
        k_attn_rec<<<dim3(16,8,4),256,0,stream>>>(
            q2s16, sq16, skv16, svT,
            k16 + (size_t)nb*262144, vTb + (size_t)nb*512,
            ts16 + (size_t)nb*262144, sa16);
        k_gemmh64<0,2,0,0><<<dim3(32,4),256,0,stream>>>(sa16, wstoutT, ema_beta,
            states_cur, nullptr, nullptr, nullptr, 2048,512,512);
      }
      k_gemmh64<1,0,0,0><<<dim3(64,4),256,0,stream>>>(ts16, wostT, nullptr,
          hstate, nullptr, nullptr, nullptr, 4096,512,512);
    }
    k_ln<<<1024,256,0,stream>>>(hstate, ff_g + l*512, xn16);
    k_gemmh<0,1,1><<<dim3(32,16),256,0,stream>>>(xn16, ffw1T + (size_t)l*1048576, ff_b1 + l*2048, nullptr, ff1_16, 4096,2048,512);
    k_gemmh64<1,0,0,0><<<dim3(64,4),256,0,stream>>>(ff1_16, ffw2T + (size_t)l*1048576, ff_b2 + l*512, hstate, nullptr, nullptr, nullptr, 4096,512,2048);
  }
  k_ln<<<1024,256,0,stream>>>(hstate, final_g, xn16);
  k_gemmh<0,0,0><<<dim3(32,157),256,0,stream>>>(xn16, wlogT, nullptr, out, nullptr, 4096,20000,512);
  k_copy<<<4096, 256, 0, stream>>>(out_states, states_cur, 1048576);
}

// Round 22
// 1413.403 us; speedup vs baseline: 1.0630x; 1.0246x over previous
//
#include <hip/hip_runtime.h>
#include <math.h>

// B=4 N=1024 V=20000 D=512 H=8 DH=64 W=512 NB=2 NS=512 FF=2048

typedef __attribute__((ext_vector_type(8))) _Float16 f16x8;
typedef __attribute__((ext_vector_type(4))) float f32x4;

__device__ __forceinline__ ushort f2h(float f){
  _Float16 h = (_Float16)f;
  return *reinterpret_cast<ushort*>(&h);
}
__device__ __forceinline__ uint pkh2(float a, float b){
  return (uint)f2h(a) | ((uint)f2h(b)<<16);
}

// ---------------- mega weight prep: 12 transposes in one launch ----------------
struct PrepDescs {
  const float* src[12];
  ushort*      dst[12];
  int K[12], N[12], nx[12], ny[12], cnt[12];
  long zs[12];
};

__global__ __launch_bounds__(256)
void k_prep_all(PrepDescs pd){
  __shared__ float tile[32][33];
  int bid = blockIdx.x, i = 0;
  while (i < 11 && bid >= pd.cnt[i]){ bid -= pd.cnt[i]; i++; }
  const int K = pd.K[i], N = pd.N[i], nx = pd.nx[i];
  const int z = bid/(nx*pd.ny[i]);
  const int rem = bid - z*nx*pd.ny[i];
  const int tyy = rem/nx, txx = rem - tyy*nx;
  const float* src = pd.src[i] + (size_t)z*K*N;
  ushort* dh = pd.dst[i] + (size_t)z*pd.zs[i];
  const int n0 = txx*32, k0 = tyy*32;
  const int tx = threadIdx.x&31, ty = threadIdx.x>>5;
#pragma unroll
  for (int u=0;u<4;u++){
    int kk = k0 + ty + u*8, nn = n0 + tx;
    tile[ty+u*8][tx] = (nn < N) ? src[(size_t)kk*N + nn] : 0.f;
  }
  __syncthreads();
#pragma unroll
  for (int u=0;u<4;u++){
    int nn = n0 + ty + u*8, kk = k0 + tx;
    dh[(size_t)nn*K + kk] = f2h(tile[tx][ty+u*8]);
  }
}

// ---------------- V transpose (startup xl mem only) ----------------
__global__ __launch_bounds__(256)
void k_vtrans(const float* __restrict__ src, ushort* __restrict__ dst,
              long sB, int sR, int sMH, long dB, long dH, int NK){
  __shared__ float tile[64][65];
  int kc = blockIdx.x, h = blockIdx.y, b = blockIdx.z;
  int t = threadIdx.x;
  int key = t>>2, doff = (t&3)*16;
  const float* sp = src + (size_t)b*sB + (size_t)(kc*64+key)*sR + (sMH? h*64:0) + doff;
#pragma unroll
  for (int u=0;u<4;u++){
    float4 v = *reinterpret_cast<const float4*>(sp + u*4);
    tile[key][doff+u*4+0]=v.x; tile[key][doff+u*4+1]=v.y;
    tile[key][doff+u*4+2]=v.z; tile[key][doff+u*4+3]=v.w;
  }
  __syncthreads();
  int d = t>>2, kf = (t&3)*16;
  ushort* dp = dst + (size_t)b*dB + (size_t)h*dH + (size_t)d*NK + kc*64 + kf;
  ushort tmp[16];
#pragma unroll
  for (int u=0;u<16;u++) tmp[u] = f2h(tile[kf+u][d]);
  uint4 o0 = make_uint4((uint)tmp[0]|((uint)tmp[1]<<16), (uint)tmp[2]|((uint)tmp[3]<<16),
                        (uint)tmp[4]|((uint)tmp[5]<<16), (uint)tmp[6]|((uint)tmp[7]<<16));
  uint4 o1 = make_uint4((uint)tmp[8]|((uint)tmp[9]<<16), (uint)tmp[10]|((uint)tmp[11]<<16),
                        (uint)tmp[12]|((uint)tmp[13]<<16),(uint)tmp[14]|((uint)tmp[15]<<16));
  *reinterpret_cast<uint4*>(dp)   = o0;
  *reinterpret_cast<uint4*>(dp+8) = o1;
}

// fp16 -> fp16 transpose (for skv16 V half)
__global__ __launch_bounds__(256)
void k_vtrans16(const ushort* __restrict__ src, ushort* __restrict__ dst,
                long sB, int sR, long dB, int NK){
  __shared__ ushort tile[64][72];
  int kc = blockIdx.x, b = blockIdx.z;
  int t = threadIdx.x;
  int key = t>>2, doff = (t&3)*16;
  const ushort* sp = src + (size_t)b*sB + (size_t)(kc*64+key)*sR + doff;
  *reinterpret_cast<uint4*>(&tile[key][doff])   = *reinterpret_cast<const uint4*>(sp);
  *reinterpret_cast<uint4*>(&tile[key][doff+8]) = *reinterpret_cast<const uint4*>(sp+8);
  __syncthreads();
  int d = t>>2, kf = (t&3)*16;
  ushort* dp = dst + (size_t)b*dB + (size_t)d*NK + kc*64 + kf;
  ushort tmp[16];
#pragma unroll
  for (int u=0;u<16;u++) tmp[u] = tile[kf+u][d];
  uint4 o0 = make_uint4((uint)tmp[0]|((uint)tmp[1]<<16), (uint)tmp[2]|((uint)tmp[3]<<16),
                        (uint)tmp[4]|((uint)tmp[5]<<16), (uint)tmp[6]|((uint)tmp[7]<<16));
  uint4 o1 = make_uint4((uint)tmp[8]|((uint)tmp[9]<<16), (uint)tmp[10]|((uint)tmp[11]<<16),
                        (uint)tmp[12]|((uint)tmp[13]<<16),(uint)tmp[14]|((uint)tmp[15]<<16));
  *reinterpret_cast<uint4*>(dp)   = o0;
  *reinterpret_cast<uint4*>(dp+8) = o1;
}

__global__ void k_cvt(ushort* __restrict__ dst, const float* __restrict__ src, int n2){
  int idx = blockIdx.x*blockDim.x + threadIdx.x;
  if (idx >= n2) return;
  reinterpret_cast<uint*>(dst)[idx] = pkh2(src[2*idx], src[2*idx+1]);
}

// ---------------- embed / postable ----------------
__global__ void k_embed(const int* __restrict__ x, const float* __restrict__ emb,
                        float* __restrict__ h, int total4){
  int idx = blockIdx.x*blockDim.x + threadIdx.x;
  if (idx >= total4) return;
  int row = idx >> 7;
  int c4  = idx & 127;
  int tok = x[row];
  reinterpret_cast<float4*>(h)[idx] =
      reinterpret_cast<const float4*>(emb)[(size_t)tok*128 + c4];
}

__global__ void k_postable(const float* __restrict__ w1, const float* __restrict__ b1,
                           const float* __restrict__ w2, const float* __restrict__ b2,
                           const float* __restrict__ w3, const float* __restrict__ b3,
                           float* __restrict__ table){
  __shared__ float h1[128];
  __shared__ float h2[128];
  int d = blockIdx.x, t = threadIdx.x;
  float a = (float)d * w1[t] + b1[t];
  h1[t] = a / (1.f + __expf(-a));
  __syncthreads();
  float acc = b2[t];
  for (int p=0;p<128;p++) acc += h1[p]*w2[p*128+t];
  h2[t] = acc / (1.f + __expf(-acc));
  __syncthreads();
  if (t < 8){
    float acc2 = b3[t];
    for (int p=0;p<128;p++) acc2 += h2[p]*w3[p*8+t];
    table[d*8+t] = acc2;
  }
}

// ---------------- layernorm -> fp16 (one wave per 512-col row, no barriers) --
__global__ void k_ln(const float* __restrict__ x, const float* __restrict__ g,
                     ushort* __restrict__ y16){
  int row = blockIdx.x*4 + (threadIdx.x>>6);
  int lane = threadIdx.x&63;
  const float* xr = x + (size_t)row*512 + lane*8;
  float4 a = *reinterpret_cast<const float4*>(xr);
  float4 b = *reinterpret_cast<const float4*>(xr+4);
  float s  = a.x+a.y+a.z+a.w + b.x+b.y+b.z+b.w;
  float ss = a.x*a.x+a.y*a.y+a.z*a.z+a.w*a.w
           + b.x*b.x+b.y*b.y+b.z*b.z+b.w*b.w;
#pragma unroll
  for (int o=1;o<64;o<<=1){ s += __shfl_xor(s,o); ss += __shfl_xor(ss,o); }
  float mu = s*(1.f/512.f);
  float var = ss*(1.f/512.f) - mu*mu;
  float rs = rsqrtf(var + 1e-5f);
  const float* gr = g + lane*8;
  float4 g0 = *reinterpret_cast<const float4*>(gr);
  float4 g1 = *reinterpret_cast<const float4*>(gr+4);
  uint4 o;
  o.x = pkh2((a.x-mu)*rs*g0.x, (a.y-mu)*rs*g0.y);
  o.y = pkh2((a.z-mu)*rs*g0.z, (a.w-mu)*rs*g0.w);
  o.z = pkh2((b.x-mu)*rs*g1.x, (b.y-mu)*rs*g1.y);
  o.w = pkh2((b.z-mu)*rs*g1.z, (b.w-mu)*rs*g1.w);
  *reinterpret_cast<uint4*>(y16 + (size_t)row*512 + lane*8) = o;
}

__device__ __forceinline__ float geluf(float x){
  float u = 1.5957691216f*(x + 0.044715f*x*x*x);
  return x / (1.f + __expf(-u));
}

// ---------------- fp16 MFMA GEMM 128x128 (FF1, logits) ----------------
template<int ACC, int EPI, int OUT16>
__global__ __launch_bounds__(256)
void k_gemmh(const ushort* __restrict__ A, const ushort* __restrict__ Bt,
             const float* __restrict__ bias, float* __restrict__ C,
             ushort* __restrict__ C16, int M, int N, int K){
  __shared__ ushort As[128][68];
  __shared__ ushort Bs[128][68];
  const int t = threadIdx.x;
  const int m0 = blockIdx.x*128, n0 = blockIdx.y*128;
  const int w = t>>6, lane = t&63;
  const int wm = (w>>1)*64, wn = (w&1)*64;
  const int fr = lane&15, fg = lane>>4;
  const int srow = t>>1, sko = (t&1)*32;

  f32x4 acc[4][4];
#pragma unroll
  for (int i=0;i<4;i++)
#pragma unroll
    for (int j=0;j<4;j++){ acc[i][j][0]=0.f; acc[i][j][1]=0.f; acc[i][j][2]=0.f; acc[i][j][3]=0.f; }

  const ushort* ap = A  + (size_t)(m0+srow)*K + sko;
  const ushort* bp = Bt + (size_t)(n0+srow)*K + sko;

  for (int k0=0; k0<K; k0+=64){
    uint4 av[4], bv[4];
#pragma unroll
    for (int u=0;u<4;u++){
      av[u] = *reinterpret_cast<const uint4*>(ap + k0 + u*8);
      bv[u] = *reinterpret_cast<const uint4*>(bp + k0 + u*8);
    }
#pragma unroll
    for (int u=0;u<4;u++){
      *reinterpret_cast<uint4*>(&As[srow][sko+u*8]) = av[u];
      *reinterpret_cast<uint4*>(&Bs[srow][sko+u*8]) = bv[u];
    }
    __syncthreads();
#pragma unroll
    for (int kk=0;kk<2;kk++){
      f16x8 af[4], bf[4];
#pragma unroll
      for (int mi=0;mi<4;mi++)
        af[mi] = *reinterpret_cast<const f16x8*>(&As[wm+mi*16+fr][kk*32+fg*8]);
#pragma unroll
      for (int nj=0;nj<4;nj++)
        bf[nj] = *reinterpret_cast<const f16x8*>(&Bs[wn+nj*16+fr][kk*32+fg*8]);
#pragma unroll
      for (int mi=0;mi<4;mi++)
#pragma unroll
        for (int nj=0;nj<4;nj++)
          acc[mi][nj] = __builtin_amdgcn_mfma_f32_16x16x32_f16(af[mi], bf[nj], acc[mi][nj], 0,0,0);
    }
    __syncthreads();
  }
#pragma unroll
  for (int mi=0;mi<4;mi++){
#pragma unroll
    for (int r=0;r<4;r++){
      int row = m0 + wm + mi*16 + fg*4 + r;
#pragma unroll
      for (int nj=0;nj<4;nj++){
        int col = n0 + wn + nj*16 + fr;
        if (col < N){
          float val = acc[mi][nj][r];
          if (bias) val += bias[col];
          if (EPI==1) val = geluf(val);
          if (OUT16){
            C16[(size_t)row*N + col] = f2h(val);
          } else {
            if (ACC) C[(size_t)row*N + col] += val; else C[(size_t)row*N + col] = val;
          }
        }
      }
    }
  }
}

// ---------------- fp16 MFMA GEMM 128x128 with split out + rms ----------------
__global__ __launch_bounds__(256)
void k_gemmqk(const ushort* __restrict__ A, const ushort* __restrict__ Bt,
              ushort* __restrict__ C1h, int ld1, int N1,
              ushort* __restrict__ C2h, int ld2,
              const float* __restrict__ qsc, const float* __restrict__ ksc,
              float* __restrict__ xlk,
              int M, int N, int K){
  __shared__ ushort As[128][68];
  __shared__ ushort Bs[128][68];
  const int t = threadIdx.x;
  const int m0 = blockIdx.x*128, n0 = blockIdx.y*128;
  const int w = t>>6, lane = t&63;
  const int wm = (w>>1)*64, wn = (w&1)*64;
  const int fr = lane&15, fg = lane>>4;
  const int srow = t>>1, sko = (t&1)*32;

  f32x4 acc[4][4];
#pragma unroll
  for (int i=0;i<4;i++)
#pragma unroll
    for (int j=0;j<4;j++){ acc[i][j][0]=0.f; acc[i][j][1]=0.f; acc[i][j][2]=0.f; acc[i][j][3]=0.f; }

  const ushort* ap = A  + (size_t)(m0+srow)*K + sko;
  const ushort* bp = Bt + (size_t)(n0+srow)*K + sko;

  for (int k0=0; k0<K; k0+=64){
    uint4 av[4], bv[4];
#pragma unroll
    for (int u=0;u<4;u++){
      av[u] = *reinterpret_cast<const uint4*>(ap + k0 + u*8);
      bv[u] = *reinterpret_cast<const uint4*>(bp + k0 + u*8);
    }
#pragma unroll
    for (int u=0;u<4;u++){
      *reinterpret_cast<uint4*>(&As[srow][sko+u*8]) = av[u];
      *reinterpret_cast<uint4*>(&Bs[srow][sko+u*8]) = bv[u];
    }
    __syncthreads();
#pragma unroll
    for (int kk=0;kk<2;kk++){
      f16x8 af[4], bf[4];
#pragma unroll
      for (int mi=0;mi<4;mi++)
        af[mi] = *reinterpret_cast<const f16x8*>(&As[wm+mi*16+fr][kk*32+fg*8]);
#pragma unroll
      for (int nj=0;nj<4;nj++)
        bf[nj] = *reinterpret_cast<const f16x8*>(&Bs[wn+nj*16+fr][kk*32+fg*8]);
#pragma unroll
      for (int mi=0;mi<4;mi++)
#pragma unroll
        for (int nj=0;nj<4;nj++)
          acc[mi][nj] = __builtin_amdgcn_mfma_f32_16x16x32_f16(af[mi], bf[nj], acc[mi][nj], 0,0,0);
    }
    __syncthreads();
  }
#pragma unroll
  for (int mi=0;mi<4;mi++){
#pragma unroll
    for (int r=0;r<4;r++){
      int row = m0 + wm + mi*16 + fg*4 + r;
      float vals[4];
#pragma unroll
      for (int nj=0;nj<4;nj++) vals[nj] = acc[mi][nj][r];
      if (qsc){
        float ss = vals[0]*vals[0]+vals[1]*vals[1]+vals[2]*vals[2]+vals[3]*vals[3];
        ss += __shfl_xor(ss,1);
        ss += __shfl_xor(ss,2);
        ss += __shfl_xor(ss,4);
        ss += __shfl_xor(ss,8);
        float rs = rsqrtf(ss + 1e-12f);
        const float* sc = ((n0+wn) < N1) ? qsc : ksc;
#pragma unroll
        for (int nj=0;nj<4;nj++) vals[nj] = vals[nj]*rs*sc[nj*16+fr];
      }
#pragma unroll
      for (int nj=0;nj<4;nj++){
        int col = n0 + wn + nj*16 + fr;
        float val = vals[nj];
        if (col < N1){
          C1h[(size_t)row*ld1 + col] = f2h(val);
        } else if (col < N){
          if (C2h) C2h[(size_t)row*ld2 + (col-N1)] = f2h(val);
          if (xlk && (row&1023) >= 512)
            xlk[((size_t)(row>>10)*512 + (row&1023) - 512)*512 + (col-N1)] = val;
        }
      }
    }
  }
}

// ---------------- fp16 MFMA GEMM 64x128 (N=512 class) ------------------------
// EPI: 0 none, 1 gelu, 2 ema (reads old from esrc, writes C).
// VT=1: fp16 transposed vT + optional fp32 xlv.
template<int ACC, int EPI, int OUT16, int VT>
__global__ __launch_bounds__(256)
void k_gemmh64(const ushort* __restrict__ A, const ushort* __restrict__ Bt,
               const float* __restrict__ bias, float* __restrict__ C,
               ushort* __restrict__ C16, ushort* __restrict__ vT,
               float* __restrict__ xlv, const float* __restrict__ esrc,
               int M, int N, int K){
  __shared__ ushort As[64][68];
  __shared__ ushort Bs[128][68];
  const int t = threadIdx.x;
  const int m0 = blockIdx.x*64, n0 = blockIdx.y*128;
  const int w = t>>6, lane = t&63;
  const int wm = (w>>1)*32, wn = (w&1)*64;
  const int fr = lane&15, fg = lane>>4;
  const int srowA = t>>2, skoA = (t&3)*16;
  const int srowB = t>>1, skoB = (t&1)*32;

  f32x4 acc[2][4];
#pragma unroll
  for (int i=0;i<2;i++)
#pragma unroll
    for (int j=0;j<4;j++){ acc[i][j][0]=0.f; acc[i][j][1]=0.f; acc[i][j][2]=0.f; acc[i][j][3]=0.f; }

  const ushort* ap = A  + (size_t)(m0+srowA)*K + skoA;
  const ushort* bp = Bt + (size_t)(n0+srowB)*K + skoB;

  for (int k0=0; k0<K; k0+=64){
    uint4 a0 = *reinterpret_cast<const uint4*>(ap + k0);
    uint4 a1 = *reinterpret_cast<const uint4*>(ap + k0 + 8);
    uint4 b0 = *reinterpret_cast<const uint4*>(bp + k0);
    uint4 b1 = *reinterpret_cast<const uint4*>(bp + k0 + 8);
    uint4 b2 = *reinterpret_cast<const uint4*>(bp + k0 + 16);
    uint4 b3 = *reinterpret_cast<const uint4*>(bp + k0 + 24);
    *reinterpret_cast<uint4*>(&As[srowA][skoA])    = a0;
    *reinterpret_cast<uint4*>(&As[srowA][skoA+8])  = a1;
    *reinterpret_cast<uint4*>(&Bs[srowB][skoB])    = b0;
    *reinterpret_cast<uint4*>(&Bs[srowB][skoB+8])  = b1;
    *reinterpret_cast<uint4*>(&Bs[srowB][skoB+16]) = b2;
    *reinterpret_cast<uint4*>(&Bs[srowB][skoB+24]) = b3;
    __syncthreads();
#pragma unroll
    for (int kk=0;kk<2;kk++){
      f16x8 af[2], bf[4];
#pragma unroll
      for (int mi=0;mi<2;mi++)
        af[mi] = *reinterpret_cast<const f16x8*>(&As[wm+mi*16+fr][kk*32+fg*8]);
#pragma unroll
      for (int nj=0;nj<4;nj++)
        bf[nj] = *reinterpret_cast<const f16x8*>(&Bs[wn+nj*16+fr][kk*32+fg*8]);
#pragma unroll
      for (int mi=0;mi<2;mi++)
#pragma unroll
        for (int nj=0;nj<4;nj++)
          acc[mi][nj] = __builtin_amdgcn_mfma_f32_16x16x32_f16(af[mi], bf[nj], acc[mi][nj], 0,0,0);
    }
    __syncthreads();
  }
#pragma unroll
  for (int mi=0;mi<2;mi++){
#pragma unroll
    for (int r=0;r<4;r++){
      int row = m0 + wm + mi*16 + fg*4 + r;
#pragma unroll
      for (int nj=0;nj<4;nj++){
        int col = n0 + wn + nj*16 + fr;
        if (col < N){
          float val = acc[mi][nj][r];
          if (EPI==2){
            size_t idx = (size_t)row*N + col;
            float old = esrc[idx];
            float dec = 1.f/(1.f+__expf(-bias[col]));
            C[idx] = dec*old + (1.f-dec)*val;
          } else {
            if (bias) val += bias[col];
            if (EPI==1) val = geluf(val);
            if (OUT16){
              if (C16) C16[(size_t)row*N + col] = f2h(val);
            } else if (C){
              if (ACC) C[(size_t)row*N + col] += val; else C[(size_t)row*N + col] = val;
            }
            if (VT && xlv && (row&1023) >= 512)
              xlv[((size_t)(row>>10)*512 + (row&1023) - 512)*512 + col] = val;
          }
        }
      }
    }
  }
  if (VT){
#pragma unroll
    for (int mi=0;mi<2;mi++)
#pragma unroll
      for (int r=0;r<4;r++)
#pragma unroll
        for (int nj=0;nj<4;nj++)
          Bs[wn+nj*16+fr][wm+mi*16+fg*4+r] = f2h(acc[mi][nj][r]);
    __syncthreads();
    int c = t>>1, half = t&1;
    int hh = (n0+c)>>6, dd = (n0+c)&63;
    int bb = m0>>10, posb = m0&1023;
    ushort* dp = vT + (size_t)bb*524288 + (size_t)hh*65536 + (size_t)dd*1024 + posb + half*32;
#pragma unroll
    for (int u=0;u<4;u++)
      *reinterpret_cast<uint4*>(dp + u*8) = *reinterpret_cast<const uint4*>(&Bs[c][half*32 + u*8]);
  }
}

// ---------------- merged windowed MFMA flash attention -----------------------
__global__ __launch_bounds__(256)
void k_attn_win(const ushort* __restrict__ q16, const ushort* __restrict__ k16,
                const ushort* __restrict__ vTb,
                const ushort* __restrict__ xlK, const ushort* __restrict__ xlVT,
                int isxl, ushort* __restrict__ O, float scale,
                const float* __restrict__ table){
  __shared__ ushort Qs[64][72];
  __shared__ ushort Ks[64][72];
  __shared__ ushort Vs[64][72];
  __shared__ ushort Pw[4][16][72];
  __shared__ float tcol[512];
  const int b = blockIdx.z, h = blockIdx.y;
  const int nb = blockIdx.x>>3, qt = blockIdx.x&7;
  const int t = threadIdx.x, w = t>>6, lane = t&63;
  const int fr = lane&15, fg = lane>>4;
  tcol[t]     = table[t*8 + h];
  tcol[t+256] = table[(t+256)*8 + h];

  const ushort* Q  = q16 + (size_t)nb*262144;
  const ushort* K1 = k16 + (size_t)nb*262144;
  const ushort* V1 = vTb + (size_t)nb*512;
  ushort* Op = O + (size_t)nb*262144;
  const int has_mem = (nb==1) || isxl;
  const ushort* K0; long k0B; const ushort* V0; long vt0B, vt0H; int vt0D;
  if (nb==1){ K0=k16; k0B=524288; V0=vTb; vt0B=524288; vt0H=65536; vt0D=1024; }
  else if (isxl){ K0=xlK; k0B=262144; V0=xlVT; vt0B=262144; vt0H=32768; vt0D=512; }
  else { K0=k16; k0B=524288; V0=vTb; vt0B=524288; vt0H=65536; vt0D=1024; }

  {
    int qrow = t>>2, doff = (t&3)*16;
    const ushort* qp = Q + (size_t)b*524288 + (size_t)(qt*64+qrow)*512 + h*64 + doff;
    *reinterpret_cast<uint4*>(&Qs[qrow][doff])   = *reinterpret_cast<const uint4*>(qp);
    *reinterpret_cast<uint4*>(&Qs[qrow][doff+8]) = *reinterpret_cast<const uint4*>(qp+8);
  }
  __syncthreads();
  f16x8 aq[2];
  aq[0] = *reinterpret_cast<const f16x8*>(&Qs[w*16+fr][fg*8]);
  aq[1] = *reinterpret_cast<const f16x8*>(&Qs[w*16+fr][32+fg*8]);

  f32x4 so[4];
#pragma unroll
  for (int dt=0;dt<4;dt++){ so[dt][0]=0.f; so[dt][1]=0.f; so[dt][2]=0.f; so[dt][3]=0.f; }
  float m[4] = {-1e30f,-1e30f,-1e30f,-1e30f};
  float lsum[4] = {0.f,0.f,0.f,0.f};

  const int srow = t>>2, sdo = (t&3)*16;
  const int vd = t>>2,   vkf = (t&3)*16;

  int jt0 = has_mem ? qt : 8;
  int jt1 = qt + 8; if (jt1 > 15) jt1 = 15;

  for (int jt=jt0; jt<=jt1; jt++){
    {
      int key = jt*64 + srow;
      const ushort* kp;
      if (key < 512) kp = K0 + (size_t)b*k0B + (size_t)key*512 + h*64 + sdo;
      else           kp = K1 + (size_t)b*524288 + (size_t)(key-512)*512 + h*64 + sdo;
      *reinterpret_cast<uint4*>(&Ks[srow][sdo])   = *reinterpret_cast<const uint4*>(kp);
      *reinterpret_cast<uint4*>(&Ks[srow][sdo+8]) = *reinterpret_cast<const uint4*>(kp+8);
    }
    {
      const ushort* vp;
      if (jt*64 < 512) vp = V0 + (size_t)b*vt0B + (size_t)h*vt0H + (size_t)vd*vt0D + jt*64 + vkf;
      else             vp = V1 + (size_t)b*524288 + (size_t)h*65536 + (size_t)vd*1024 + (jt*64-512) + vkf;
      *reinterpret_cast<uint4*>(&Vs[vd][vkf])   = *reinterpret_cast<const uint4*>(vp);
      *reinterpret_cast<uint4*>(&Vs[vd][vkf+8]) = *reinterpret_cast<const uint4*>(vp+8);
    }
    __syncthreads();
    f32x4 sacc[4];
#pragma unroll
    for (int kt=0;kt<4;kt++){ sacc[kt][0]=0.f; sacc[kt][1]=0.f; sacc[kt][2]=0.f; sacc[kt][3]=0.f; }
#pragma unroll
    for (int ks=0;ks<2;ks++){
#pragma unroll
      for (int kt=0;kt<4;kt++){
        f16x8 bf = *reinterpret_cast<const f16x8*>(&Ks[kt*16+fr][ks*32+fg*8]);
        sacc[kt] = __builtin_amdgcn_mfma_f32_16x16x32_f16(aq[ks], bf, sacc[kt], 0,0,0);
      }
    }
#pragma unroll
    for (int r=0;r<4;r++){
      float sv[4];
      int ia = qt*64 + w*16 + fg*4 + r;
#pragma unroll
      for (int kt=0;kt<4;kt++){
        float s = sacc[kt][r]*scale;
        int jg = jt*64 + kt*16 + fr;
        bool valid = (jg > ia) && (jg <= ia+512) && (has_mem || jg >= 512);
        sv[kt] = valid ? s + tcol[ia+512-jg] : -1e9f;
      }
      float tm = fmaxf(fmaxf(sv[0],sv[1]), fmaxf(sv[2],sv[3]));
      tm = fmaxf(tm, __shfl_xor(tm,1));
      tm = fmaxf(tm, __shfl_xor(tm,2));
      tm = fmaxf(tm, __shfl_xor(tm,4));
      tm = fmaxf(tm, __shfl_xor(tm,8));
      float mn = fmaxf(m[r], tm);
      float c = __expf(m[r]-mn);
      m[r] = mn;
      float ps = 0.f;
#pragma unroll
      for (int kt=0;kt<4;kt++){
        float pp = (sv[kt] <= -1e8f) ? 0.f : __expf(sv[kt]-mn);
        ps += pp;
        Pw[w][fg*4+r][kt*16+fr] = f2h(pp);
      }
      ps += __shfl_xor(ps,1);
      ps += __shfl_xor(ps,2);
      ps += __shfl_xor(ps,4);
      ps += __shfl_xor(ps,8);
      lsum[r] = lsum[r]*c + ps;
#pragma unroll
      for (int dt=0;dt<4;dt++) so[dt][r] *= c;
    }
#pragma unroll
    for (int ks=0;ks<2;ks++){
      f16x8 pa = *reinterpret_cast<const f16x8*>(&Pw[w][fr][ks*32+fg*8]);
#pragma unroll
      for (int dt=0;dt<4;dt++){
        f16x8 bv = *reinterpret_cast<const f16x8*>(&Vs[dt*16+fr][ks*32+fg*8]);
        so[dt] = __builtin_amdgcn_mfma_f32_16x16x32_f16(pa, bv, so[dt], 0,0,0);
      }
    }
    __syncthreads();
  }
#pragma unroll
  for (int r=0;r<4;r++){
    int row = qt*64 + w*16 + fg*4 + r;
    float inv = 1.f / lsum[r];
    ushort* op = Op + (size_t)b*524288 + (size_t)row*512 + h*64;
#pragma unroll
    for (int dt=0;dt<4;dt++)
      op[dt*16+fr] = f2h(so[dt][r]*inv);
  }
}

// ---------------- merged rec-layer attentions ----------------
__global__ __launch_bounds__(256)
void k_attn_rec(const ushort* __restrict__ q2s, long q2sB,
                const ushort* __restrict__ sq,
                const ushort* __restrict__ skv, const ushort* __restrict__ svT,
                const ushort* __restrict__ kblk, const ushort* __restrict__ vblk,
                ushort* __restrict__ ts, ushort* __restrict__ sa){
  __shared__ ushort Qs[64][72];
  __shared__ ushort Ks[64][72];
  __shared__ ushort Vs[64][72];
  __shared__ ushort Pw[4][16][72];
  const int b = blockIdx.z, h = blockIdx.y;
  const int task = blockIdx.x>>3, qt = blockIdx.x&7;
  const int t = threadIdx.x, w = t>>6, lane = t&63;
  const int fr = lane&15, fg = lane>>4;

  const ushort* Q; long qB; const ushort* K1; int k1R, k1H;
  const ushort* VT1; long vt1B, vt1H; int vt1D;
  int nt; ushort* O; long oB;
  if (task==0){
    Q=q2s; qB=q2sB; K1=skv; k1R=128; k1H=0;
    VT1=svT; vt1B=32768; vt1H=0; vt1D=512;
    nt=8; O=ts; oB=524288;
  } else {
    Q=sq; qB=262144; K1=kblk; k1R=512; k1H=1;
    VT1=vblk; vt1B=524288; vt1H=65536; vt1D=1024;
    nt=16; O=sa; oB=262144;
  }

  {
    int qrow = t>>2, doff = (t&3)*16;
    const ushort* qp = Q + (size_t)b*qB + (size_t)(qt*64+qrow)*512 + h*64 + doff;
    *reinterpret_cast<uint4*>(&Qs[qrow][doff])   = *reinterpret_cast<const uint4*>(qp);
    *reinterpret_cast<uint4*>(&Qs[qrow][doff+8]) = *reinterpret_cast<const uint4*>(qp+8);
  }
  __syncthreads();
  f16x8 aq[2];
  aq[0] = *reinterpret_cast<const f16x8*>(&Qs[w*16+fr][fg*8]);
  aq[1] = *reinterpret_cast<const f16x8*>(&Qs[w*16+fr][32+fg*8]);

  f32x4 so[4];
#pragma unroll
  for (int dt=0;dt<4;dt++){ so[dt][0]=0.f; so[dt][1]=0.f; so[dt][2]=0.f; so[dt][3]=0.f; }
  float m[4] = {-1e30f,-1e30f,-1e30f,-1e30f};
  float lsum[4] = {0.f,0.f,0.f,0.f};

  const int srow = t>>2, sdo = (t&3)*16;
  const int vd = t>>2,   vkf = (t&3)*16;

  for (int jt=0; jt<nt; jt++){
    {
      int key = jt*64 + srow;
      const ushort* kp;
      if (key < 512) kp = skv + (size_t)b*65536 + (size_t)key*128 + sdo;
      else           kp = K1 + (size_t)b*524288 + (size_t)(key-512)*k1R + (k1H? h*64:0) + sdo;
      *reinterpret_cast<uint4*>(&Ks[srow][sdo])   = *reinterpret_cast<const uint4*>(kp);
      *reinterpret_cast<uint4*>(&Ks[srow][sdo+8]) = *reinterpret_cast<const uint4*>(kp+8);
    }
    {
      const ushort* vp;
      if (jt*64 < 512) vp = svT + (size_t)b*32768 + (size_t)vd*512 + jt*64 + vkf;
      else             vp = VT1 + (size_t)b*vt1B + (size_t)h*vt1H + (size_t)vd*vt1D + (jt*64-512) + vkf;
      *reinterpret_cast<uint4*>(&Vs[vd][vkf])   = *reinterpret_cast<const uint4*>(vp);
      *reinterpret_cast<uint4*>(&Vs[vd][vkf+8]) = *reinterpret_cast<const uint4*>(vp+8);
    }
    __syncthreads();
    f32x4 sacc[4];
#pragma unroll
    for (int kt=0;kt<4;kt++){ sacc[kt][0]=0.f; sacc[kt][1]=0.f; sacc[kt][2]=0.f; sacc[kt][3]=0.f; }
#pragma unroll
    for (int ks=0;ks<2;ks++){
#pragma unroll
      for (int kt=0;kt<4;kt++){
        f16x8 bf = *reinterpret_cast<const f16x8*>(&Ks[kt*16+fr][ks*32+fg*8]);
        sacc[kt] = __builtin_amdgcn_mfma_f32_16x16x32_f16(aq[ks], bf, sacc[kt], 0,0,0);
      }
    }
#pragma unroll
    for (int r=0;r<4;r++){
      float sv[4];
#pragma unroll
      for (int kt=0;kt<4;kt++) sv[kt] = sacc[kt][r]*0.125f;
      float tm = fmaxf(fmaxf(sv[0],sv[1]), fmaxf(sv[2],sv[3]));
      tm = fmaxf(tm, __shfl_xor(tm,1));
      tm = fmaxf(tm, __shfl_xor(tm,2));
      tm = fmaxf(tm, __shfl_xor(tm,4));
      tm = fmaxf(tm, __shfl_xor(tm,8));
      float mn = fmaxf(m[r], tm);
      float c = __expf(m[r]-mn);
      m[r] = mn;
      float ps = 0.f;
#pragma unroll
      for (int kt=0;kt<4;kt++){
        float pp = __expf(sv[kt]-mn);
        ps += pp;
        Pw[w][fg*4+r][kt*16+fr] = f2h(pp);
      }
      ps += __shfl_xor(ps,1);
      ps += __shfl_xor(ps,2);
      ps += __shfl_xor(ps,4);
      ps += __shfl_xor(ps,8);
      lsum[r] = lsum[r]*c + ps;
#pragma unroll
      for (int dt=0;dt<4;dt++) so[dt][r] *= c;
    }
#pragma unroll
    for (int ks=0;ks<2;ks++){
      f16x8 pa = *reinterpret_cast<const f16x8*>(&Pw[w][fr][ks*32+fg*8]);
#pragma unroll
      for (int dt=0;dt<4;dt++){
        f16x8 bv = *reinterpret_cast<const f16x8*>(&Vs[dt*16+fr][ks*32+fg*8]);
        so[dt] = __builtin_amdgcn_mfma_f32_16x16x32_f16(pa, bv, so[dt], 0,0,0);
      }
    }
    __syncthreads();
  }
#pragma unroll
  for (int r=0;r<4;r++){
    int row = qt*64 + w*16 + fg*4 + r;
    float inv = 1.f / lsum[r];
    ushort* op = O + (size_t)b*oB + (size_t)row*512 + h*64;
#pragma unroll
    for (int dt=0;dt<4;dt++)
      op[dt*16+fr] = f2h(so[dt][r]*inv);
  }
}

// ---------------- launcher ----------------
extern "C" void kernel_launch(void* const* d_in, const int* in_sizes, int n_in,
                              void* d_out, int out_size, void* d_ws, size_t ws_size,
                              hipStream_t stream){
  // floats 12,599,296 B + ushorts 106,954,752 B = 119,554,048 B
  if (ws_size < (size_t)119554048) return;

  const int*   x        = (const int*)  d_in[0];
  const float* tok_emb  = (const float*)d_in[1];
  const float* pw1 = (const float*)d_in[2];
  const float* pb1 = (const float*)d_in[3];
  const float* pw2 = (const float*)d_in[4];
  const float* pb2 = (const float*)d_in[5];
  const float* pw3 = (const float*)d_in[6];
  const float* pb3 = (const float*)d_in[7];
  const float* ln_g = (const float*)d_in[8];
  const float* Wq = (const float*)d_in[9];
  const float* Wk = (const float*)d_in[10];
  const float* Wv = (const float*)d_in[11];
  const float* Wo = (const float*)d_in[12];
  const float* q_scale = (const float*)d_in[13];
  const float* k_scale = (const float*)d_in[14];
  const float* Wo_state = (const float*)d_in[15];
  const float* state_norm_g = (const float*)d_in[16];
  const float* Wq2s = (const float*)d_in[17];
  const float* Ws2q = (const float*)d_in[18];
  const float* Ws2kv = (const float*)d_in[19];
  const float* W_state_out = (const float*)d_in[20];
  const float* ema_beta = (const float*)d_in[21];
  const float* ff_g = (const float*)d_in[22];
  const float* ff_w1 = (const float*)d_in[23];
  const float* ff_b1 = (const float*)d_in[24];
  const float* ff_w2 = (const float*)d_in[25];
  const float* ff_b2 = (const float*)d_in[26];
  const float* final_g = (const float*)d_in[27];
  const float* W_logits = (const float*)d_in[28];
  const float* xl_mem_k = (const float*)d_in[29];
  const float* xl_mem_v = (const float*)d_in[30];
  const float* states_in = (const float*)d_in[31];

  float* out = (float*)d_out;
  float* out_xlk    = out + 81920000;
  float* out_xlv    = out + 84017152;
  float* out_states = out + 86114304;

  float* p = (float*)d_ws;
  float* hstate   = p; p += 2097152;
  float* states_cur = p; p += 1048576;
  float* table    = p; p += 4096;

  ushort* us = (ushort*)p;
  ushort* wqkh  = us; us += 3145728;   // [6][1024][512]: rows 0-511 q, 512-1023 k
  ushort* wvT   = us; us += 1572864;
  ushort* woT   = us; us += 1572864;
  ushort* ffw1T = us; us += 6291456;
  ushort* ffw2T = us; us += 6291456;
  ushort* wostT = us; us += 262144;
  ushort* wstoutT = us; us += 262144;
  ushort* wq2sh = us; us += 262144;
  ushort* wsqkvh = us; us += 327680;   // [640][512]: rows 0-511 Ws2q, 512-639 Ws2kv
  ushort* wlogT  = us; us += 10289152; // [20096][512]
  ushort* vTb   = us; us += 2097152;   // [b][h][64][1024]
  ushort* xlvT  = us; us += 2097152;   // [2][b][h][64][512]
  ushort* svT   = us; us += 131072;    // [b][64][512]
  ushort* xn16  = us; us += 2097152;
  ushort* ao16  = us; us += 2097152;
  ushort* ff1_16 = us; us += 8388608;  // [4096][2048] + rec aliases
  ushort* q16   = us; us += 2097152;
  ushort* k16   = us; us += 2097152;
  ushort* xlk16 = us; us += 2097152;   // [2][b][512][512] fp16
  // rec aliases inside ff1_16 (dead between FF uses)
  ushort* ts16    = ff1_16;             // [4096][512]
  ushort* sa16    = ff1_16 + 2097152;   // [2048][512]
  ushort* sn16    = ff1_16 + 3145728;   // [2048][512]
  ushort* sq16    = ff1_16 + 4194304;   // [2048][512]
  ushort* q2s_all = ff1_16 + 5242880;   // [4096][512]
  ushort* skv16   = ff1_16 + 7340032;   // [2048][128] -> ends 7602176 < 8388608

  // ---- mega weight prep (single launch) ----
  PrepDescs pd;
  auto setd = [&](int i, const float* s, ushort* d, int K, int N, int nx, int ny, int nz, long zs){
    pd.src[i]=s; pd.dst[i]=d; pd.K[i]=K; pd.N[i]=N; pd.nx[i]=nx; pd.ny[i]=ny;
    pd.cnt[i]=nx*ny*nz; pd.zs[i]=zs;
  };
  setd(0,  Wq,          wqkh,           512,512,  16,16,6, 524288);
  setd(1,  Wk,          wqkh+262144,    512,512,  16,16,6, 524288);
  setd(2,  Wv,          wvT,            512,512,  16,16,6, 262144);
  setd(3,  Wo,          woT,            512,512,  16,16,6, 262144);
  setd(4,  ff_w1,       ffw1T,          512,2048, 64,16,6, 1048576);
  setd(5,  ff_w2,       ffw2T,          2048,512, 16,64,6, 1048576);
  setd(6,  Wo_state,    wostT,          512,512,  16,16,1, 262144);
  setd(7,  W_state_out, wstoutT,        512,512,  16,16,1, 262144);
  setd(8,  Wq2s,        wq2sh,          512,512,  16,16,1, 262144);
  setd(9,  Ws2q,        wsqkvh,         512,512,  16,16,1, 327680);
  setd(10, Ws2kv,       wsqkvh+262144,  512,128,  4,16,1,  327680);
  setd(11, W_logits,    wlogT,          512,20000,628,16,1,10289152);
  k_prep_all<<<29568,256,0,stream>>>(pd);

  for (int s=0;s<2;s++)
    k_vtrans<<<dim3(8,8,4),256,0,stream>>>(xl_mem_v + (size_t)s*1048576,
                                           xlvT + (size_t)s*1048576,
                                           262144L, 512, 1, 262144L, 32768L, 512);
  k_cvt<<<4096,256,0,stream>>>(xlk16, xl_mem_k, 1048576);

  k_embed<<<2048, 256, 0, stream>>>(x, tok_emb, hstate, 524288);
  k_postable<<<512, 128, 0, stream>>>(pw1,pb1,pw2,pb2,pw3,pb3, table);

  for (int l=0;l<6;l++){
    bool isxl = (l==4 || l==5);
    int xli = l-4;
    int src = (l==4)? 1 : 0;     // roll(-1)
    k_ln<<<1024,256,0,stream>>>(hstate, ln_g + l*512, xn16);
    float scale = 0.125f;
    const float* qsc = nullptr; const float* ksc = nullptr;
    if (l>=3){ qsc = q_scale + l*64; ksc = k_scale + l*64; scale = 8.f; }
    k_gemmqk<<<dim3(32,8),256,0,stream>>>(xn16,
        wqkh + (size_t)l*524288,
        q16, 512, 512, k16, 512, qsc, ksc,
        isxl ? out_xlk + (size_t)xli*1048576 : nullptr,
        4096, 1024, 512);
    k_gemmh64<0,0,0,1><<<dim3(64,4),256,0,stream>>>(xn16, wvT + (size_t)l*262144,
        nullptr, nullptr, nullptr, vTb,
        isxl ? out_xlv + (size_t)xli*1048576 : nullptr, nullptr, 4096,512,512);

    k_attn_win<<<dim3(16,8,4),256,0,stream>>>(
        q16, k16, vTb,
        isxl ? xlk16 + (size_t)src*1048576 : k16,
        isxl ? xlvT  + (size_t)src*1048576 : vTb,
        isxl ? 1 : 0, ao16, scale, table);

    k_gemmh64<1,0,0,0><<<dim3(64,4),256,0,stream>>>(ao16, woT + (size_t)l*262144,
        nullptr, hstate, nullptr, nullptr, nullptr, nullptr, 4096,512,512);
    if (l==3){
      // q2s for BOTH blocks: one GEMM over all 4096 xn rows (states-independent)
      k_gemmqk<<<dim3(32,4),256,0,stream>>>(xn16, wq2sh,
          q2s_all, 512, 512, nullptr, 0, nullptr, nullptr, nullptr, 4096, 512, 512);
      for (int nb=0;nb<2;nb++){
        const float* st_src = (nb==0) ? states_in : states_cur;
        float* st_dst = (nb==0) ? states_cur : out_states;
        k_ln<<<512,256,0,stream>>>(st_src, state_norm_g, sn16);
        k_gemmqk<<<dim3(16,5),256,0,stream>>>(sn16, wsqkvh,
            sq16, 512, 512, skv16, 128, nullptr, nullptr, nullptr, 2048, 640, 512);
        k_vtrans16<<<dim3(8,1,4),256,0,stream>>>(skv16 + 64, svT, 65536L, 128, 32768L, 512);
        k_attn_rec<<<dim3(16,8,4),256,0,stream>>>(
            q2s_all + (size_t)nb*262144, 524288L,
            sq16, skv16, svT,
            k16 + (size_t)nb*262144, vTb + (size_t)nb*512,
            ts16 + (size_t)nb*262144, sa16);
        k_gemmh64<0,2,0,0><<<dim3(32,4),256,0,stream>>>(sa16, wstoutT, ema_beta,
            st_dst, nullptr, nullptr, nullptr, st_src, 2048,512,512);
      }
      k_gemmh64<1,0,0,0><<<dim3(64,4),256,0,stream>>>(ts16, wostT, nullptr,
          hstate, nullptr, nullptr, nullptr, nullptr, 4096,512,512);
    }
    k_ln<<<1024,256,0,stream>>>(hstate, ff_g + l*512, xn16);
    k_gemmh<0,1,1><<<dim3(32,16),256,0,stream>>>(xn16, ffw1T + (size_t)l*1048576, ff_b1 + l*2048, nullptr, ff1_16, 4096,2048,512);
    k_gemmh64<1,0,0,0><<<dim3(64,4),256,0,stream>>>(ff1_16, ffw2T + (size_t)l*1048576, ff_b2 + l*512, hstate, nullptr, nullptr, nullptr, nullptr, 4096,512,2048);
  }
  k_ln<<<1024,256,0,stream>>>(hstate, final_g, xn16);
  k_gemmh<0,0,0><<<dim3(32,157),256,0,stream>>>(xn16, wlogT, nullptr, out, nullptr, 4096,20000,512);
}